// Round 6
// baseline (986.979 us; speedup 1.0000x reference)
//
#include <hip/hip_runtime.h>
#include <cstdint>
#include <cstddef>

typedef __bf16 bf16;
typedef __bf16 bf16x8 __attribute__((ext_vector_type(8)));
typedef float f32x4 __attribute__((ext_vector_type(4)));

__device__ __forceinline__ void gload_lds16(const bf16* g, bf16* l) {
    __builtin_amdgcn_global_load_lds((const __attribute__((address_space(1))) void*)g,
                                     (__attribute__((address_space(3))) void*)l, 16, 0, 0);
}

// ---------------- f32 -> bf16 conversion ----------------
__global__ void cvt_f32_bf16_kernel(const float* __restrict__ in, bf16* __restrict__ outp, size_t n) {
    const size_t i = ((size_t)blockIdx.x * 256 + threadIdx.x) * 8;
    if (i >= n) return;
    const float4 a = *(const float4*)(in + i);
    const float4 b = *(const float4*)(in + i + 4);
    bf16x8 o;
    o[0] = (bf16)a.x; o[1] = (bf16)a.y; o[2] = (bf16)a.z; o[3] = (bf16)a.w;
    o[4] = (bf16)b.x; o[5] = (bf16)b.y; o[6] = (bf16)b.z; o[7] = (bf16)b.w;
    *(bf16x8*)(outp + i) = o;
}

// ---------------- all 4 weight transposes in one launch ----------------
__global__ void wtrans_all_kernel(const float* __restrict__ W1, bf16* __restrict__ T1,
                                  const float* __restrict__ W2, bf16* __restrict__ T2,
                                  const float* __restrict__ W3, bf16* __restrict__ T3,
                                  const float* __restrict__ Wo, bf16* __restrict__ To)
{
    __shared__ bf16 tile[64][65];
    const int id = blockIdx.x;
    const int t = threadIdx.x;
    const float* W; bf16* T; int K, N, kb, nb;
    if (id < 216)      { W = W1; T = T1; K = 1152; N = 768;  const int r = id;       kb = r % 18; nb = r / 18; }
    else if (id < 312) { W = W2; T = T2; K = 768;  N = 512;  const int r = id - 216; kb = r % 12; nb = r / 12; }
    else if (id < 344) { W = W3; T = T3; K = 512;  N = 256;  const int r = id - 312; kb = r % 8;  nb = r / 8;  }
    else               { W = Wo; T = To; K = 256;  N = 1152; const int r = id - 344; kb = r % 4;  nb = r / 4;  }
    const int k0 = kb << 6;
    const int n0 = nb << 6;
#pragma unroll
    for (int i = 0; i < 16; ++i) {
        const int flat = i * 256 + t;
        const int r = flat >> 6;
        const int c = flat & 63;
        tile[c][r] = (bf16)W[(size_t)(k0 + r) * N + n0 + c];
    }
    __syncthreads();
#pragma unroll
    for (int i = 0; i < 16; ++i) {
        const int flat = i * 256 + t;
        const int r = flat >> 6;
        const int c = flat & 63;
        T[(size_t)(n0 + r) * K + k0 + c] = tile[r][c];
    }
}

// XCD-aware bijective swizzle (requires nwg % 8 == 0)
__device__ __forceinline__ int xcd_swz(int bid, int nwg) {
    return (bid & 7) * (nwg >> 3) + (bid >> 3);
}

// ---------------- 8-phase 256x256 GEMM (m201-style), BK=64, 512 threads ----------------
// 8 waves = 2M x 4N, wave tile 128x64. LDS: 2 bufs x (A 256x64 | B 256x64) = 128 KB.
// Per K-tile: 4 phases (C-quadrants), each {ds-reads || stage -> barrier -> 16 MFMA -> barrier}.
// Quarter-staging placed strictly after the last reader phase (race-free by barrier ordering).
// vmcnt(8) once per K-tile: 8 loads/thread/tile in flight => tile kt+1 proven landed.
__global__ __launch_bounds__(512, 2)
void gemm_8ph_kernel(const bf16* __restrict__ A, const bf16* __restrict__ Bt,
                     const float* __restrict__ bias, bf16* __restrict__ C,
                     int K, int N, int nx, int do_gelu)
{
    __shared__ bf16 lds[2 * 32768];
    const int t = threadIdx.x;
    const int w = t >> 6, l = t & 63;
    const int l15 = l & 15, l4 = l >> 4;
    const int wm = w >> 2, wn = w & 3;
    const int wgid = xcd_swz(blockIdx.x, gridDim.x);
    const int mblk = wgid / nx, nblk = wgid - mblk * nx;
    const int m0 = mblk << 8, n0 = nblk << 8;

    const int srow = t >> 3;                   // row within 64-row quarter
    const int sgrp = (t & 7) ^ (srow & 7);     // inverse-swizzled source 16B-group
    const int NT = K >> 6;

    auto stageA = [&](int kt, int q) {
        gload_lds16(A + (size_t)(m0 + (q << 6) + srow) * K + (kt << 6) + (sgrp << 3),
                    &lds[((kt & 1) << 15) + (q << 12) + (w << 9)]);
    };
    auto stageB = [&](int kt, int q) {
        gload_lds16(Bt + (size_t)(n0 + (q << 6) + srow) * K + (kt << 6) + (sgrp << 3),
                    &lds[((kt & 1) << 15) + 16384 + (q << 12) + (w << 9)]);
    };

    f32x4 acc[8][4] = {};

    // prologue: stage tiles 0 and 1 (8 loads/thread each)
#pragma unroll
    for (int q = 0; q < 4; ++q) stageA(0, q);
#pragma unroll
    for (int q = 0; q < 4; ++q) stageB(0, q);
#pragma unroll
    for (int q = 0; q < 4; ++q) stageA(1, q);
#pragma unroll
    for (int q = 0; q < 4; ++q) stageB(1, q);
    asm volatile("s_waitcnt vmcnt(8)" ::: "memory");   // tile 0 landed
    __builtin_amdgcn_s_barrier();

    for (int kt = 0; kt < NT; ++kt) {
        const bf16* lA = &lds[(kt & 1) << 15];
        const bf16* lB = lA + 16384;
        const bool pf = (kt + 2) < NT;

        bf16x8 aLo[8], aHi[8], bb[8];

        // ---- ph1: quadrant (m-lo, n-lo); reads A-mlo(8) + B-nlo(4) ----
#pragma unroll
        for (int i = 0; i < 4; ++i) {
            const int r = (wm << 7) + (i << 4) + l15;
            aLo[i]     = *(const bf16x8*)&lA[(r << 6) + ((l4 ^ (r & 7)) << 3)];
            aLo[i + 4] = *(const bf16x8*)&lA[(r << 6) + (((4 + l4) ^ (r & 7)) << 3)];
        }
#pragma unroll
        for (int j = 0; j < 2; ++j) {
            const int r = (wn << 6) + (j << 4) + l15;
            bb[j]     = *(const bf16x8*)&lB[(r << 6) + ((l4 ^ (r & 7)) << 3)];
            bb[j + 2] = *(const bf16x8*)&lB[(r << 6) + (((4 + l4) ^ (r & 7)) << 3)];
        }
        __builtin_amdgcn_s_barrier();
        __builtin_amdgcn_s_setprio(1);
#pragma unroll
        for (int i = 0; i < 4; ++i)
#pragma unroll
            for (int j = 0; j < 2; ++j) {
                acc[i][j] = __builtin_amdgcn_mfma_f32_16x16x32_bf16(aLo[i], bb[j], acc[i][j], 0, 0, 0);
                acc[i][j] = __builtin_amdgcn_mfma_f32_16x16x32_bf16(aLo[i + 4], bb[j + 2], acc[i][j], 0, 0, 0);
            }
        __builtin_amdgcn_s_setprio(0);
        __builtin_amdgcn_s_barrier();

        // ---- ph2: quadrant (m-hi, n-lo); reads A-mhi(8); stage QA0,QA2 of kt+2 ----
#pragma unroll
        for (int i = 0; i < 4; ++i) {
            const int r = (wm << 7) + ((i + 4) << 4) + l15;
            aHi[i]     = *(const bf16x8*)&lA[(r << 6) + ((l4 ^ (r & 7)) << 3)];
            aHi[i + 4] = *(const bf16x8*)&lA[(r << 6) + (((4 + l4) ^ (r & 7)) << 3)];
        }
        if (pf) { stageA(kt + 2, 0); stageA(kt + 2, 2); }
        __builtin_amdgcn_s_barrier();
        __builtin_amdgcn_s_setprio(1);
#pragma unroll
        for (int i = 0; i < 4; ++i)
#pragma unroll
            for (int j = 0; j < 2; ++j) {
                acc[i + 4][j] = __builtin_amdgcn_mfma_f32_16x16x32_bf16(aHi[i], bb[j], acc[i + 4][j], 0, 0, 0);
                acc[i + 4][j] = __builtin_amdgcn_mfma_f32_16x16x32_bf16(aHi[i + 4], bb[j + 2], acc[i + 4][j], 0, 0, 0);
            }
        __builtin_amdgcn_s_setprio(0);
        __builtin_amdgcn_s_barrier();

        // ---- ph3: quadrant (m-lo, n-hi); reads B-nhi(4); stage QA1,QA3 ----
#pragma unroll
        for (int j = 0; j < 2; ++j) {
            const int r = (wn << 6) + ((j + 2) << 4) + l15;
            bb[j + 4] = *(const bf16x8*)&lB[(r << 6) + ((l4 ^ (r & 7)) << 3)];
            bb[j + 6] = *(const bf16x8*)&lB[(r << 6) + (((4 + l4) ^ (r & 7)) << 3)];
        }
        if (pf) { stageA(kt + 2, 1); stageA(kt + 2, 3); }
        __builtin_amdgcn_s_barrier();
        __builtin_amdgcn_s_setprio(1);
#pragma unroll
        for (int i = 0; i < 4; ++i)
#pragma unroll
            for (int j = 0; j < 2; ++j) {
                acc[i][j + 2] = __builtin_amdgcn_mfma_f32_16x16x32_bf16(aLo[i], bb[j + 4], acc[i][j + 2], 0, 0, 0);
                acc[i][j + 2] = __builtin_amdgcn_mfma_f32_16x16x32_bf16(aLo[i + 4], bb[j + 6], acc[i][j + 2], 0, 0, 0);
            }
        __builtin_amdgcn_s_setprio(0);
        __builtin_amdgcn_s_barrier();

        // ---- ph4: quadrant (m-hi, n-hi); stage QB0..3 ----
        if (pf) { stageB(kt + 2, 0); stageB(kt + 2, 1); stageB(kt + 2, 2); stageB(kt + 2, 3); }
        __builtin_amdgcn_s_barrier();
        __builtin_amdgcn_s_setprio(1);
#pragma unroll
        for (int i = 0; i < 4; ++i)
#pragma unroll
            for (int j = 0; j < 2; ++j) {
                acc[i + 4][j + 2] = __builtin_amdgcn_mfma_f32_16x16x32_bf16(aHi[i], bb[j + 4], acc[i + 4][j + 2], 0, 0, 0);
                acc[i + 4][j + 2] = __builtin_amdgcn_mfma_f32_16x16x32_bf16(aHi[i + 4], bb[j + 6], acc[i + 4][j + 2], 0, 0, 0);
            }
        __builtin_amdgcn_s_setprio(0);
        if (kt + 1 < NT) {
            if (pf) { asm volatile("s_waitcnt vmcnt(8)" ::: "memory"); }
            else    { asm volatile("s_waitcnt vmcnt(0)" ::: "memory"); }
            __builtin_amdgcn_s_barrier();
        }
    }

    // epilogue
#pragma unroll
    for (int mi = 0; mi < 8; ++mi) {
        const int mb = m0 + (wm << 7) + (mi << 4) + (l4 << 2);
#pragma unroll
        for (int ni = 0; ni < 4; ++ni) {
            const int col = n0 + (wn << 6) + (ni << 4) + l15;
            const float bv = bias[col];
#pragma unroll
            for (int r = 0; r < 4; ++r) {
                float v = acc[mi][ni][r] + bv;
                if (do_gelu) v = 0.5f * v * (1.0f + erff(v * 0.70710678118654752f));
                C[(size_t)(mb + r) * N + col] = (bf16)v;
            }
        }
    }
}

// ---------------- 128x128 GEMM (proven) for N=1152 output layer ----------------
__global__ void gemm_bf16_kernel(const bf16* __restrict__ A, const bf16* __restrict__ Bt,
                                 const float* __restrict__ bias, bf16* __restrict__ C,
                                 int K, int N, int nx, int do_gelu)
{
    __shared__ bf16 Alds[128 * 64];
    __shared__ bf16 Blds[128 * 64];
    const int t = threadIdx.x;
    const int w = t >> 6;
    const int l = t & 63;
    const int l15 = l & 15, l4 = l >> 4;
    const int wgid = xcd_swz(blockIdx.x, gridDim.x);
    const int mblk = wgid / nx;
    const int nblk = wgid - mblk * nx;
    const int m0 = mblk << 7;
    const int n0 = nblk << 7;
    const int wm = (w >> 1) << 6;
    const int wn = (w & 1) << 6;

    f32x4 acc[4][4] = {};

    int sr[4], sg[4];
#pragma unroll
    for (int i = 0; i < 4; ++i) {
        const int flat = i * 256 + t;
        sr[i] = flat >> 3;
        sg[i] = ((flat & 7) ^ (sr[i] & 7)) << 3;
    }

    for (int k0 = 0; k0 < K; k0 += 64) {
#pragma unroll
        for (int i = 0; i < 4; ++i) {
            gload_lds16(A + (size_t)(m0 + sr[i]) * K + (k0 + sg[i]),
                        &Alds[(size_t)(i * 256 + (w << 6)) << 3]);
            gload_lds16(Bt + (size_t)(n0 + sr[i]) * K + (k0 + sg[i]),
                        &Blds[(size_t)(i * 256 + (w << 6)) << 3]);
        }
        __syncthreads();
#pragma unroll
        for (int kk = 0; kk < 2; ++kk) {
            bf16x8 af[4], bfv[4];
#pragma unroll
            for (int i = 0; i < 4; ++i) {
                const int r = wm + (i << 4) + l15;
                const int g = (kk << 2) + l4;
                af[i] = *(const bf16x8*)&Alds[(r << 6) + ((g ^ (r & 7)) << 3)];
                const int rn = wn + (i << 4) + l15;
                bfv[i] = *(const bf16x8*)&Blds[(rn << 6) + ((g ^ (rn & 7)) << 3)];
            }
#pragma unroll
            for (int i = 0; i < 4; ++i)
#pragma unroll
                for (int j = 0; j < 4; ++j)
                    acc[i][j] = __builtin_amdgcn_mfma_f32_16x16x32_bf16(af[i], bfv[j], acc[i][j], 0, 0, 0);
        }
        __syncthreads();
    }

#pragma unroll
    for (int i = 0; i < 4; ++i) {
        const int mb = m0 + wm + (i << 4) + (l4 << 2);
#pragma unroll
        for (int j = 0; j < 4; ++j) {
            const int col = n0 + wn + (j << 4) + l15;
            const float bv = bias[col];
#pragma unroll
            for (int r = 0; r < 4; ++r) {
                float v = acc[i][j][r] + bv;
                if (do_gelu) v = 0.5f * v * (1.0f + erff(v * 0.70710678118654752f));
                C[(size_t)(mb + r) * N + col] = (bf16)v;
            }
        }
    }
}

// ---------------- LayerNorms ----------------
__global__ void ln768_kernel(bf16* __restrict__ H, const float* __restrict__ g,
                             const float* __restrict__ be)
{
    const int t = threadIdx.x;
    const int rloc = t >> 7;
    const int u = t & 127;
    bf16* hp = H + ((size_t)blockIdx.x * 2 + rloc) * 768;
    float v[8];
    float s1 = 0.f, s2 = 0.f;
    if (u < 96) {
        const bf16x8 hv = *(const bf16x8*)(hp + u * 8);
#pragma unroll
        for (int e = 0; e < 8; ++e) { v[e] = (float)hv[e]; s1 += v[e]; s2 += v[e] * v[e]; }
    }
#pragma unroll
    for (int m = 1; m < 64; m <<= 1) { s1 += __shfl_xor(s1, m, 64); s2 += __shfl_xor(s2, m, 64); }
    __shared__ float red[8];
    const int w = t >> 6;
    if ((t & 63) == 0) { red[w] = s1; red[w + 4] = s2; }
    __syncthreads();
    const int wb = rloc << 1;
    s1 = red[wb] + red[wb + 1];
    s2 = red[wb + 4] + red[wb + 5];
    const float mu = s1 * (1.0f / 768.0f);
    const float rstd = rsqrtf(s2 * (1.0f / 768.0f) - mu * mu + 1e-5f);
    if (u < 96) {
        const float4 g0 = *(const float4*)(g + u * 8);
        const float4 g1 = *(const float4*)(g + u * 8 + 4);
        const float4 b0 = *(const float4*)(be + u * 8);
        const float4 b1 = *(const float4*)(be + u * 8 + 4);
        bf16x8 o;
        o[0] = (bf16)((v[0] - mu) * rstd * g0.x + b0.x);
        o[1] = (bf16)((v[1] - mu) * rstd * g0.y + b0.y);
        o[2] = (bf16)((v[2] - mu) * rstd * g0.z + b0.z);
        o[3] = (bf16)((v[3] - mu) * rstd * g0.w + b0.w);
        o[4] = (bf16)((v[4] - mu) * rstd * g1.x + b1.x);
        o[5] = (bf16)((v[5] - mu) * rstd * g1.y + b1.y);
        o[6] = (bf16)((v[6] - mu) * rstd * g1.z + b1.z);
        o[7] = (bf16)((v[7] - mu) * rstd * g1.w + b1.w);
        *(bf16x8*)(hp + u * 8) = o;
    }
}

__global__ void ln512_kernel(bf16* __restrict__ H, const float* __restrict__ g,
                             const float* __restrict__ be)
{
    const int t = threadIdx.x;
    const int w = t >> 6, l = t & 63;
    bf16* hp = H + ((size_t)blockIdx.x * 4 + w) * 512;
    const bf16x8 hv = *(const bf16x8*)(hp + l * 8);
    float v[8];
    float s1 = 0.f, s2 = 0.f;
#pragma unroll
    for (int e = 0; e < 8; ++e) { v[e] = (float)hv[e]; s1 += v[e]; s2 += v[e] * v[e]; }
#pragma unroll
    for (int m = 1; m < 64; m <<= 1) { s1 += __shfl_xor(s1, m, 64); s2 += __shfl_xor(s2, m, 64); }
    const float mu = s1 * (1.0f / 512.0f);
    const float rstd = rsqrtf(s2 * (1.0f / 512.0f) - mu * mu + 1e-5f);
    const float4 g0 = *(const float4*)(g + l * 8);
    const float4 g1 = *(const float4*)(g + l * 8 + 4);
    const float4 b0 = *(const float4*)(be + l * 8);
    const float4 b1 = *(const float4*)(be + l * 8 + 4);
    bf16x8 o;
    o[0] = (bf16)((v[0] - mu) * rstd * g0.x + b0.x);
    o[1] = (bf16)((v[1] - mu) * rstd * g0.y + b0.y);
    o[2] = (bf16)((v[2] - mu) * rstd * g0.z + b0.z);
    o[3] = (bf16)((v[3] - mu) * rstd * g0.w + b0.w);
    o[4] = (bf16)((v[4] - mu) * rstd * g1.x + b1.x);
    o[5] = (bf16)((v[5] - mu) * rstd * g1.y + b1.y);
    o[6] = (bf16)((v[6] - mu) * rstd * g1.z + b1.z);
    o[7] = (bf16)((v[7] - mu) * rstd * g1.w + b1.w);
    *(bf16x8*)(hp + l * 8) = o;
}

__global__ void ln256_kernel(bf16* __restrict__ H, const float* __restrict__ g,
                             const float* __restrict__ be)
{
    const int t = threadIdx.x;
    const int rloc = t >> 5, l = t & 31;
    bf16* hp = H + ((size_t)blockIdx.x * 8 + rloc) * 256;
    const bf16x8 hv = *(const bf16x8*)(hp + l * 8);
    float v[8];
    float s1 = 0.f, s2 = 0.f;
#pragma unroll
    for (int e = 0; e < 8; ++e) { v[e] = (float)hv[e]; s1 += v[e]; s2 += v[e] * v[e]; }
#pragma unroll
    for (int m = 1; m < 32; m <<= 1) { s1 += __shfl_xor(s1, m, 64); s2 += __shfl_xor(s2, m, 64); }
    const float mu = s1 * (1.0f / 256.0f);
    const float rstd = rsqrtf(s2 * (1.0f / 256.0f) - mu * mu + 1e-5f);
    const float4 g0 = *(const float4*)(g + l * 8);
    const float4 g1 = *(const float4*)(g + l * 8 + 4);
    const float4 b0 = *(const float4*)(be + l * 8);
    const float4 b1 = *(const float4*)(be + l * 8 + 4);
    bf16x8 o;
    o[0] = (bf16)((v[0] - mu) * rstd * g0.x + b0.x);
    o[1] = (bf16)((v[1] - mu) * rstd * g0.y + b0.y);
    o[2] = (bf16)((v[2] - mu) * rstd * g0.z + b0.z);
    o[3] = (bf16)((v[3] - mu) * rstd * g0.w + b0.w);
    o[4] = (bf16)((v[4] - mu) * rstd * g1.x + b1.x);
    o[5] = (bf16)((v[5] - mu) * rstd * g1.y + b1.y);
    o[6] = (bf16)((v[6] - mu) * rstd * g1.z + b1.z);
    o[7] = (bf16)((v[7] - mu) * rstd * g1.w + b1.w);
    *(bf16x8*)(hp + l * 8) = o;
}

// ---------------- pooled mean (pass 2 fused into se) ----------------
__global__ void pool1_kernel(const bf16* __restrict__ Y, float* __restrict__ ppart) {
    const int c = blockIdx.x * 128 + threadIdx.x;
    const int nc = blockIdx.y;
    const int b = blockIdx.z;
    const bf16* yp = Y + ((size_t)b * 9216 + (size_t)nc * 256) * 1152 + c;
    float s = 0.f;
#pragma unroll 4
    for (int i = 0; i < 256; ++i) s += (float)yp[(size_t)i * 1152];
    ppart[((size_t)b * 36 + nc) * 1152 + c] = s;
}

// ---------------- SE MLP ----------------
__global__ void se_kernel(const float* __restrict__ ppart,
                          const float* __restrict__ w1, const float* __restrict__ b1,
                          const float* __restrict__ w2, const float* __restrict__ b2,
                          float* __restrict__ sbuf)
{
    const int b = blockIdx.x, t = threadIdx.x;
    __shared__ float p[1152];
    __shared__ float t1[144];
    for (int c = t; c < 1152; c += 256) {
        float s = 0.f;
#pragma unroll
        for (int j = 0; j < 36; ++j) s += ppart[((size_t)b * 36 + j) * 1152 + c];
        p[c] = s * (1.0f / 9216.0f);
    }
    __syncthreads();
    if (t < 144) {
        float a = b1[t];
        for (int k = 0; k < 1152; ++k) a += p[k] * w1[k * 144 + t];
        t1[t] = a > 0.f ? a : 0.f;
    }
    __syncthreads();
    for (int c = t; c < 1152; c += 256) {
        float a = b2[c];
#pragma unroll 8
        for (int k = 0; k < 144; ++k) a += t1[k] * w2[k * 1152 + c];
        sbuf[b * 1152 + c] = 1.0f / (1.0f + expf(-a));
    }
}

// ---------------- windowed self-attention ----------------
__device__ __forceinline__ int fswz(int r) { return (r & 7) ^ ((r >> 3) & 3); }

__global__ void attn_kernel(const bf16* __restrict__ Y, const float* __restrict__ sbuf,
                            float* __restrict__ out)
{
    __shared__ bf16 yw[32 * 384];
    __shared__ float Sp[4][32][33];
    __shared__ bf16 P[32 * 32];

    const int t = threadIdx.x;
    const int w = t >> 6, l = t & 63;
    const int l15 = l & 15, l4 = l >> 4;
    const int wdx = blockIdx.x, b = blockIdx.y;

    const bf16* Yp = Y + ((size_t)b * 9216 + (size_t)wdx * 32) * 1152;
    const float* sv = sbuf + b * 1152;
    float* op = out + ((size_t)b * 9216 + (size_t)wdx * 32) * 1152;

    auto stage_chunk = [&](int cc) {
#pragma unroll
        for (int i = 0; i < 6; ++i) {
            const int flat = i * 256 + t;
            const int r = flat / 48;
            const int gg = flat - r * 48;
            const int c0 = cc * 384 + gg * 8;
            const bf16x8 yv = *(const bf16x8*)(Yp + (size_t)r * 1152 + c0);
            const float4 sa = *(const float4*)(sv + c0);
            const float4 sb = *(const float4*)(sv + c0 + 4);
            bf16x8 ov;
            ov[0] = (bf16)((float)yv[0] * sa.x);
            ov[1] = (bf16)((float)yv[1] * sa.y);
            ov[2] = (bf16)((float)yv[2] * sa.z);
            ov[3] = (bf16)((float)yv[3] * sa.w);
            ov[4] = (bf16)((float)yv[4] * sb.x);
            ov[5] = (bf16)((float)yv[5] * sb.y);
            ov[6] = (bf16)((float)yv[6] * sb.z);
            ov[7] = (bf16)((float)yv[7] * sb.w);
            *(bf16x8*)&yw[((r * 48) + (gg ^ fswz(r))) << 3] = ov;
        }
    };

    f32x4 acc[2][2] = {};
    for (int cc = 0; cc < 3; ++cc) {
        if (cc) __syncthreads();
        stage_chunk(cc);
        __syncthreads();
#pragma unroll
        for (int kkl = 0; kkl < 3; ++kkl) {
            const int g = ((w * 3 + kkl) << 2) + l4;
            bf16x8 af[2];
#pragma unroll
            for (int i = 0; i < 2; ++i) {
                const int r = (i << 4) + l15;
                af[i] = *(const bf16x8*)&yw[((r * 48) + (g ^ fswz(r))) << 3];
            }
#pragma unroll
            for (int i = 0; i < 2; ++i)
#pragma unroll
                for (int j = 0; j < 2; ++j)
                    acc[i][j] = __builtin_amdgcn_mfma_f32_16x16x32_bf16(af[i], af[j], acc[i][j], 0, 0, 0);
        }
    }
#pragma unroll
    for (int i = 0; i < 2; ++i)
#pragma unroll
        for (int j = 0; j < 2; ++j)
#pragma unroll
            for (int r = 0; r < 4; ++r)
                Sp[w][(i << 4) + (l4 << 2) + r][(j << 4) + l15] = acc[i][j][r];
    __syncthreads();

    {
        const int q = t >> 3, u = t & 7;
        float v[4];
#pragma unroll
        for (int e = 0; e < 4; ++e) {
            const int k2 = (u << 2) + e;
            v[e] = (Sp[0][q][k2] + Sp[1][q][k2] + Sp[2][q][k2] + Sp[3][q][k2]) * 0.029462782549439483f;
        }
        float mx = fmaxf(fmaxf(v[0], v[1]), fmaxf(v[2], v[3]));
#pragma unroll
        for (int m = 1; m < 8; m <<= 1) mx = fmaxf(mx, __shfl_xor(mx, m, 64));
        float sm = 0.f;
#pragma unroll
        for (int e = 0; e < 4; ++e) { v[e] = expf(v[e] - mx); sm += v[e]; }
#pragma unroll
        for (int m = 1; m < 8; m <<= 1) sm += __shfl_xor(sm, m, 64);
        const float inv = 1.0f / sm;
#pragma unroll
        for (int e = 0; e < 4; ++e) P[(q << 5) + (u << 2) + e] = (bf16)(v[e] * inv);
    }
    __syncthreads();

    bf16x8 pa[2];
#pragma unroll
    for (int i = 0; i < 2; ++i)
        pa[i] = *(const bf16x8*)&P[(((i << 4) + l15) << 5) + (l4 << 3)];

    for (int ci = 0; ci < 3; ++ci) {
        const int cc = (ci == 0) ? 2 : (ci - 1);
        if (ci) {
            __syncthreads();
            stage_chunk(cc);
            __syncthreads();
        }
        f32x4 pacc[2][6] = {};
#pragma unroll
        for (int jn = 0; jn < 6; ++jn) {
            const int nl = w * 96 + (jn << 4) + l15;
            const int gg = nl >> 3, e = nl & 7;
            bf16x8 bv;
#pragma unroll
            for (int j = 0; j < 8; ++j) {
                const int kr = (l4 << 3) + j;
                bv[j] = yw[(((kr * 48) + (gg ^ fswz(kr))) << 3) + e];
            }
#pragma unroll
            for (int i = 0; i < 2; ++i)
                pacc[i][jn] = __builtin_amdgcn_mfma_f32_16x16x32_bf16(pa[i], bv, pacc[i][jn], 0, 0, 0);
        }
#pragma unroll
        for (int i = 0; i < 2; ++i) {
            const int mb = (i << 4) + (l4 << 2);
#pragma unroll
            for (int jn = 0; jn < 6; ++jn) {
                const int cg = cc * 384 + w * 96 + (jn << 4) + l15;
#pragma unroll
                for (int r = 0; r < 4; ++r)
                    op[(size_t)(mb + r) * 1152 + cg] = pacc[i][jn][r];
            }
        }
    }
}

// ---------------- launcher ----------------
extern "C" void kernel_launch(void* const* d_in, const int* in_sizes, int n_in,
                              void* d_out, int out_size, void* d_ws, size_t ws_size,
                              hipStream_t stream)
{
    const float* x   = (const float*)d_in[0];
    const float* W1  = (const float*)d_in[1];
    const float* b1  = (const float*)d_in[2];
    const float* g1  = (const float*)d_in[3];
    const float* be1 = (const float*)d_in[4];
    const float* W2  = (const float*)d_in[5];
    const float* b2  = (const float*)d_in[6];
    const float* g2  = (const float*)d_in[7];
    const float* be2 = (const float*)d_in[8];
    const float* W3  = (const float*)d_in[9];
    const float* b3  = (const float*)d_in[10];
    const float* g3  = (const float*)d_in[11];
    const float* be3 = (const float*)d_in[12];
    const float* Wo  = (const float*)d_in[13];
    const float* bo  = (const float*)d_in[14];
    const float* cw1 = (const float*)d_in[15];
    const float* cb1 = (const float*)d_in[16];
    const float* cw2 = (const float*)d_in[17];
    const float* cb2 = (const float*)d_in[18];
    float* out = (float*)d_out;

    const int M = 8 * 9216;  // 73728 rows
    size_t off = 0;
    auto alloc = [&](size_t nbytes) {
        void* p = (char*)d_ws + off;
        off += (nbytes + 255) & ~(size_t)255;
        return p;
    };
    bf16* Yb  = (bf16*)alloc((size_t)M * 1152 * 2);  // x-bf16 early, Y late
    bf16* Hb  = (bf16*)alloc((size_t)M * 768 * 2);   // H1; later reused as H3
    bf16* H2  = (bf16*)alloc((size_t)M * 512 * 2);
    bf16* Wt1 = (bf16*)alloc(768ull * 1152 * 2);
    bf16* Wt2 = (bf16*)alloc(512ull * 768 * 2);
    bf16* Wt3 = (bf16*)alloc(256ull * 512 * 2);
    bf16* Wto = (bf16*)alloc(1152ull * 256 * 2);
    float* ppart = (float*)alloc(8ull * 36 * 1152 * 4);
    float* sbuf  = (float*)alloc(8ull * 1152 * 4);
    bf16* Xb = Yb;
    bf16* H1 = Hb;
    bf16* H3 = Hb;

    cvt_f32_bf16_kernel<<<41472, 256, 0, stream>>>(x, Xb, (size_t)M * 1152);
    wtrans_all_kernel<<<416, 256, 0, stream>>>(W1, Wt1, W2, Wt2, W3, Wt3, Wo, Wto);

    gemm_8ph_kernel<<<288 * 3, 512, 0, stream>>>(Xb, Wt1, b1, H1, 1152, 768, 3, 1);
    ln768_kernel<<<M / 2, 256, 0, stream>>>(H1, g1, be1);
    gemm_8ph_kernel<<<288 * 2, 512, 0, stream>>>(H1, Wt2, b2, H2, 768, 512, 2, 1);
    ln512_kernel<<<M / 4, 256, 0, stream>>>(H2, g2, be2);
    gemm_8ph_kernel<<<288 * 1, 512, 0, stream>>>(H2, Wt3, b3, H3, 512, 256, 1, 1);
    ln256_kernel<<<M / 8, 256, 0, stream>>>(H3, g3, be3);
    gemm_bf16_kernel<<<576 * 9, 256, 0, stream>>>(H3, Wto, bo, Yb, 256, 1152, 9, 0);

    pool1_kernel<<<dim3(9, 36, 8), 128, 0, stream>>>(Yb, ppart);
    se_kernel<<<8, 256, 0, stream>>>(ppart, cw1, cb1, cw2, cb2, sbuf);
    attn_kernel<<<dim3(288, 8), 256, 0, stream>>>(Yb, sbuf, out);
}

// Round 7
// 984.797 us; speedup vs baseline: 1.0022x; 1.0022x over previous
//
#include <hip/hip_runtime.h>
#include <cstdint>
#include <cstddef>

typedef __bf16 bf16;
typedef __bf16 bf16x4 __attribute__((ext_vector_type(4)));
typedef __bf16 bf16x8 __attribute__((ext_vector_type(8)));
typedef float f32x4 __attribute__((ext_vector_type(4)));

__device__ __forceinline__ void gload_lds16(const bf16* g, bf16* l) {
    __builtin_amdgcn_global_load_lds((const __attribute__((address_space(1))) void*)g,
                                     (__attribute__((address_space(3))) void*)l, 16, 0, 0);
}

// ---------------- f32 -> bf16 conversion ----------------
__global__ void cvt_f32_bf16_kernel(const float* __restrict__ in, bf16* __restrict__ outp, size_t n) {
    const size_t i = ((size_t)blockIdx.x * 256 + threadIdx.x) * 8;
    if (i >= n) return;
    const float4 a = *(const float4*)(in + i);
    const float4 b = *(const float4*)(in + i + 4);
    bf16x8 o;
    o[0] = (bf16)a.x; o[1] = (bf16)a.y; o[2] = (bf16)a.z; o[3] = (bf16)a.w;
    o[4] = (bf16)b.x; o[5] = (bf16)b.y; o[6] = (bf16)b.z; o[7] = (bf16)b.w;
    *(bf16x8*)(outp + i) = o;
}

// ---------------- all 4 weight transposes in one launch ----------------
__global__ void wtrans_all_kernel(const float* __restrict__ W1, bf16* __restrict__ T1,
                                  const float* __restrict__ W2, bf16* __restrict__ T2,
                                  const float* __restrict__ W3, bf16* __restrict__ T3,
                                  const float* __restrict__ Wo, bf16* __restrict__ To)
{
    __shared__ bf16 tile[64][65];
    const int id = blockIdx.x;
    const int t = threadIdx.x;
    const float* W; bf16* T; int K, N, kb, nb;
    if (id < 216)      { W = W1; T = T1; K = 1152; N = 768;  const int r = id;       kb = r % 18; nb = r / 18; }
    else if (id < 312) { W = W2; T = T2; K = 768;  N = 512;  const int r = id - 216; kb = r % 12; nb = r / 12; }
    else if (id < 344) { W = W3; T = T3; K = 512;  N = 256;  const int r = id - 312; kb = r % 8;  nb = r / 8;  }
    else               { W = Wo; T = To; K = 256;  N = 1152; const int r = id - 344; kb = r % 4;  nb = r / 4;  }
    const int k0 = kb << 6;
    const int n0 = nb << 6;
#pragma unroll
    for (int i = 0; i < 16; ++i) {
        const int flat = i * 256 + t;
        const int r = flat >> 6;
        const int c = flat & 63;
        tile[c][r] = (bf16)W[(size_t)(k0 + r) * N + n0 + c];
    }
    __syncthreads();
#pragma unroll
    for (int i = 0; i < 16; ++i) {
        const int flat = i * 256 + t;
        const int r = flat >> 6;
        const int c = flat & 63;
        T[(size_t)(n0 + r) * K + k0 + c] = tile[r][c];
    }
}

// XCD-aware bijective swizzle (requires nwg % 8 == 0)
__device__ __forceinline__ int xcd_swz(int bid, int nwg) {
    return (bid & 7) * (nwg >> 3) + (bid >> 3);
}

// ---------------- GEMM (bf16 A): C[M][N] = A @ Bt^T + bias, optional exact GELU ----------------
__global__ void gemm_bf16_kernel(const bf16* __restrict__ A, const bf16* __restrict__ Bt,
                                 const float* __restrict__ bias, bf16* __restrict__ C,
                                 int K, int N, int nx, int do_gelu)
{
    __shared__ bf16 Alds[128 * 64];
    __shared__ bf16 Blds[128 * 64];
    const int t = threadIdx.x;
    const int w = t >> 6;
    const int l = t & 63;
    const int l15 = l & 15, l4 = l >> 4;
    const int wgid = xcd_swz(blockIdx.x, gridDim.x);
    const int mblk = wgid / nx;
    const int nblk = wgid - mblk * nx;
    const int m0 = mblk << 7;
    const int n0 = nblk << 7;
    const int wm = (w >> 1) << 6;
    const int wn = (w & 1) << 6;

    f32x4 acc[4][4] = {};

    int sr[4], sg[4];
#pragma unroll
    for (int i = 0; i < 4; ++i) {
        const int flat = i * 256 + t;
        sr[i] = flat >> 3;
        sg[i] = ((flat & 7) ^ (sr[i] & 7)) << 3;
    }

    for (int k0 = 0; k0 < K; k0 += 64) {
#pragma unroll
        for (int i = 0; i < 4; ++i) {
            gload_lds16(A + (size_t)(m0 + sr[i]) * K + (k0 + sg[i]),
                        &Alds[(size_t)(i * 256 + (w << 6)) << 3]);
            gload_lds16(Bt + (size_t)(n0 + sr[i]) * K + (k0 + sg[i]),
                        &Blds[(size_t)(i * 256 + (w << 6)) << 3]);
        }
        __syncthreads();
#pragma unroll
        for (int kk = 0; kk < 2; ++kk) {
            bf16x8 af[4], bfv[4];
#pragma unroll
            for (int i = 0; i < 4; ++i) {
                const int r = wm + (i << 4) + l15;
                const int g = (kk << 2) + l4;
                af[i] = *(const bf16x8*)&Alds[(r << 6) + ((g ^ (r & 7)) << 3)];
                const int rn = wn + (i << 4) + l15;
                bfv[i] = *(const bf16x8*)&Blds[(rn << 6) + ((g ^ (rn & 7)) << 3)];
            }
#pragma unroll
            for (int i = 0; i < 4; ++i)
#pragma unroll
                for (int j = 0; j < 4; ++j)
                    acc[i][j] = __builtin_amdgcn_mfma_f32_16x16x32_bf16(af[i], bfv[j], acc[i][j], 0, 0, 0);
        }
        __syncthreads();
    }

#pragma unroll
    for (int i = 0; i < 4; ++i) {
        const int mb = m0 + wm + (i << 4) + (l4 << 2);
#pragma unroll
        for (int j = 0; j < 4; ++j) {
            const int col = n0 + wn + (j << 4) + l15;
            const float bv = bias[col];
#pragma unroll
            for (int r = 0; r < 4; ++r) {
                float v = acc[i][j][r] + bv;
                if (do_gelu) v = 0.5f * v * (1.0f + erff(v * 0.70710678118654752f));
                C[(size_t)(mb + r) * N + col] = (bf16)v;
            }
        }
    }
}

// ---------------- LayerNorms ----------------
__global__ void ln768_kernel(bf16* __restrict__ H, const float* __restrict__ g,
                             const float* __restrict__ be)
{
    const int t = threadIdx.x;
    const int rloc = t >> 7;
    const int u = t & 127;
    bf16* hp = H + ((size_t)blockIdx.x * 2 + rloc) * 768;
    float v[8];
    float s1 = 0.f, s2 = 0.f;
    if (u < 96) {
        const bf16x8 hv = *(const bf16x8*)(hp + u * 8);
#pragma unroll
        for (int e = 0; e < 8; ++e) { v[e] = (float)hv[e]; s1 += v[e]; s2 += v[e] * v[e]; }
    }
#pragma unroll
    for (int m = 1; m < 64; m <<= 1) { s1 += __shfl_xor(s1, m, 64); s2 += __shfl_xor(s2, m, 64); }
    __shared__ float red[8];
    const int w = t >> 6;
    if ((t & 63) == 0) { red[w] = s1; red[w + 4] = s2; }
    __syncthreads();
    const int wb = rloc << 1;
    s1 = red[wb] + red[wb + 1];
    s2 = red[wb + 4] + red[wb + 5];
    const float mu = s1 * (1.0f / 768.0f);
    const float rstd = rsqrtf(s2 * (1.0f / 768.0f) - mu * mu + 1e-5f);
    if (u < 96) {
        const float4 g0 = *(const float4*)(g + u * 8);
        const float4 g1 = *(const float4*)(g + u * 8 + 4);
        const float4 b0 = *(const float4*)(be + u * 8);
        const float4 b1 = *(const float4*)(be + u * 8 + 4);
        bf16x8 o;
        o[0] = (bf16)((v[0] - mu) * rstd * g0.x + b0.x);
        o[1] = (bf16)((v[1] - mu) * rstd * g0.y + b0.y);
        o[2] = (bf16)((v[2] - mu) * rstd * g0.z + b0.z);
        o[3] = (bf16)((v[3] - mu) * rstd * g0.w + b0.w);
        o[4] = (bf16)((v[4] - mu) * rstd * g1.x + b1.x);
        o[5] = (bf16)((v[5] - mu) * rstd * g1.y + b1.y);
        o[6] = (bf16)((v[6] - mu) * rstd * g1.z + b1.z);
        o[7] = (bf16)((v[7] - mu) * rstd * g1.w + b1.w);
        *(bf16x8*)(hp + u * 8) = o;
    }
}

__global__ void ln512_kernel(bf16* __restrict__ H, const float* __restrict__ g,
                             const float* __restrict__ be)
{
    const int t = threadIdx.x;
    const int w = t >> 6, l = t & 63;
    bf16* hp = H + ((size_t)blockIdx.x * 4 + w) * 512;
    const bf16x8 hv = *(const bf16x8*)(hp + l * 8);
    float v[8];
    float s1 = 0.f, s2 = 0.f;
#pragma unroll
    for (int e = 0; e < 8; ++e) { v[e] = (float)hv[e]; s1 += v[e]; s2 += v[e] * v[e]; }
#pragma unroll
    for (int m = 1; m < 64; m <<= 1) { s1 += __shfl_xor(s1, m, 64); s2 += __shfl_xor(s2, m, 64); }
    const float mu = s1 * (1.0f / 512.0f);
    const float rstd = rsqrtf(s2 * (1.0f / 512.0f) - mu * mu + 1e-5f);
    const float4 g0 = *(const float4*)(g + l * 8);
    const float4 g1 = *(const float4*)(g + l * 8 + 4);
    const float4 b0 = *(const float4*)(be + l * 8);
    const float4 b1 = *(const float4*)(be + l * 8 + 4);
    bf16x8 o;
    o[0] = (bf16)((v[0] - mu) * rstd * g0.x + b0.x);
    o[1] = (bf16)((v[1] - mu) * rstd * g0.y + b0.y);
    o[2] = (bf16)((v[2] - mu) * rstd * g0.z + b0.z);
    o[3] = (bf16)((v[3] - mu) * rstd * g0.w + b0.w);
    o[4] = (bf16)((v[4] - mu) * rstd * g1.x + b1.x);
    o[5] = (bf16)((v[5] - mu) * rstd * g1.y + b1.y);
    o[6] = (bf16)((v[6] - mu) * rstd * g1.z + b1.z);
    o[7] = (bf16)((v[7] - mu) * rstd * g1.w + b1.w);
    *(bf16x8*)(hp + l * 8) = o;
}

__global__ void ln256_kernel(bf16* __restrict__ H, const float* __restrict__ g,
                             const float* __restrict__ be)
{
    const int t = threadIdx.x;
    const int rloc = t >> 5, l = t & 31;
    bf16* hp = H + ((size_t)blockIdx.x * 8 + rloc) * 256;
    const bf16x8 hv = *(const bf16x8*)(hp + l * 8);
    float v[8];
    float s1 = 0.f, s2 = 0.f;
#pragma unroll
    for (int e = 0; e < 8; ++e) { v[e] = (float)hv[e]; s1 += v[e]; s2 += v[e] * v[e]; }
#pragma unroll
    for (int m = 1; m < 32; m <<= 1) { s1 += __shfl_xor(s1, m, 64); s2 += __shfl_xor(s2, m, 64); }
    const float mu = s1 * (1.0f / 256.0f);
    const float rstd = rsqrtf(s2 * (1.0f / 256.0f) - mu * mu + 1e-5f);
    const float4 g0 = *(const float4*)(g + l * 8);
    const float4 g1 = *(const float4*)(g + l * 8 + 4);
    const float4 b0 = *(const float4*)(be + l * 8);
    const float4 b1 = *(const float4*)(be + l * 8 + 4);
    bf16x8 o;
    o[0] = (bf16)((v[0] - mu) * rstd * g0.x + b0.x);
    o[1] = (bf16)((v[1] - mu) * rstd * g0.y + b0.y);
    o[2] = (bf16)((v[2] - mu) * rstd * g0.z + b0.z);
    o[3] = (bf16)((v[3] - mu) * rstd * g0.w + b0.w);
    o[4] = (bf16)((v[4] - mu) * rstd * g1.x + b1.x);
    o[5] = (bf16)((v[5] - mu) * rstd * g1.y + b1.y);
    o[6] = (bf16)((v[6] - mu) * rstd * g1.z + b1.z);
    o[7] = (bf16)((v[7] - mu) * rstd * g1.w + b1.w);
    *(bf16x8*)(hp + l * 8) = o;
}

// ---------------- pooled mean (pass 2 fused into se) ----------------
__global__ void pool1_kernel(const bf16* __restrict__ Y, float* __restrict__ ppart) {
    const int c = blockIdx.x * 128 + threadIdx.x;
    const int nc = blockIdx.y;
    const int b = blockIdx.z;
    const bf16* yp = Y + ((size_t)b * 9216 + (size_t)nc * 256) * 1152 + c;
    float s = 0.f;
#pragma unroll 4
    for (int i = 0; i < 256; ++i) s += (float)yp[(size_t)i * 1152];
    ppart[((size_t)b * 36 + nc) * 1152 + c] = s;
}

// ---------------- SE MLP ----------------
__global__ void se_kernel(const float* __restrict__ ppart,
                          const float* __restrict__ w1, const float* __restrict__ b1,
                          const float* __restrict__ w2, const float* __restrict__ b2,
                          float* __restrict__ sbuf)
{
    const int b = blockIdx.x, t = threadIdx.x;
    __shared__ float p[1152];
    __shared__ float t1[144];
    for (int c = t; c < 1152; c += 256) {
        float s = 0.f;
#pragma unroll
        for (int j = 0; j < 36; ++j) s += ppart[((size_t)b * 36 + j) * 1152 + c];
        p[c] = s * (1.0f / 9216.0f);
    }
    __syncthreads();
    if (t < 144) {
        float a = b1[t];
        for (int k = 0; k < 1152; ++k) a += p[k] * w1[k * 144 + t];
        t1[t] = a > 0.f ? a : 0.f;
    }
    __syncthreads();
    for (int c = t; c < 1152; c += 256) {
        float a = b2[c];
#pragma unroll 8
        for (int k = 0; k < 144; ++k) a += t1[k] * w2[k * 1152 + c];
        sbuf[b * 1152 + c] = 1.0f / (1.0f + expf(-a));
    }
}

// ---------------- windowed self-attention ----------------
// yw: row-major chunk (QK^T operands, XOR-swizzled 16B groups)
// ywT: transposed chunk [col][k], rows padded to 44 elems (88B: b64-aligned reads,
//      write banks spread) -> PV B-frags become 2x ds_read_b64 instead of 48 scalar u16 gathers.
__device__ __forceinline__ int fswz(int r) { return (r & 7) ^ ((r >> 3) & 3); }

__global__ void attn_kernel(const bf16* __restrict__ Y, const float* __restrict__ sbuf,
                            float* __restrict__ out)
{
    __shared__ bf16 yw[32 * 384];
    __shared__ bf16 ywT[384 * 44];
    __shared__ float Sp[4][32][33];
    __shared__ bf16 P[32 * 32];

    const int t = threadIdx.x;
    const int w = t >> 6, l = t & 63;
    const int l15 = l & 15, l4 = l >> 4;
    const int wdx = blockIdx.x, b = blockIdx.y;

    const bf16* Yp = Y + ((size_t)b * 9216 + (size_t)wdx * 32) * 1152;
    const float* sv = sbuf + b * 1152;
    float* op = out + ((size_t)b * 9216 + (size_t)wdx * 32) * 1152;

    auto stage_chunk = [&](int cc) {
#pragma unroll
        for (int i = 0; i < 6; ++i) {
            const int flat = i * 256 + t;
            const int r = flat / 48;
            const int gg = flat - r * 48;
            const int c0 = cc * 384 + gg * 8;
            const bf16x8 yv = *(const bf16x8*)(Yp + (size_t)r * 1152 + c0);
            const float4 sa = *(const float4*)(sv + c0);
            const float4 sb = *(const float4*)(sv + c0 + 4);
            bf16x8 ov;
            ov[0] = (bf16)((float)yv[0] * sa.x);
            ov[1] = (bf16)((float)yv[1] * sa.y);
            ov[2] = (bf16)((float)yv[2] * sa.z);
            ov[3] = (bf16)((float)yv[3] * sa.w);
            ov[4] = (bf16)((float)yv[4] * sb.x);
            ov[5] = (bf16)((float)yv[5] * sb.y);
            ov[6] = (bf16)((float)yv[6] * sb.z);
            ov[7] = (bf16)((float)yv[7] * sb.w);
            *(bf16x8*)&yw[((r * 48) + (gg ^ fswz(r))) << 3] = ov;
            // transposed copy (chunk-local col = gg*8+e, row k = r)
#pragma unroll
            for (int e = 0; e < 8; ++e)
                ywT[(gg * 8 + e) * 44 + r] = ov[e];
        }
    };

    f32x4 acc[2][2] = {};
    for (int cc = 0; cc < 3; ++cc) {
        if (cc) __syncthreads();
        stage_chunk(cc);
        __syncthreads();
#pragma unroll
        for (int kkl = 0; kkl < 3; ++kkl) {
            const int g = ((w * 3 + kkl) << 2) + l4;
            bf16x8 af[2];
#pragma unroll
            for (int i = 0; i < 2; ++i) {
                const int r = (i << 4) + l15;
                af[i] = *(const bf16x8*)&yw[((r * 48) + (g ^ fswz(r))) << 3];
            }
#pragma unroll
            for (int i = 0; i < 2; ++i)
#pragma unroll
                for (int j = 0; j < 2; ++j)
                    acc[i][j] = __builtin_amdgcn_mfma_f32_16x16x32_bf16(af[i], af[j], acc[i][j], 0, 0, 0);
        }
    }
#pragma unroll
    for (int i = 0; i < 2; ++i)
#pragma unroll
        for (int j = 0; j < 2; ++j)
#pragma unroll
            for (int r = 0; r < 4; ++r)
                Sp[w][(i << 4) + (l4 << 2) + r][(j << 4) + l15] = acc[i][j][r];
    __syncthreads();

    {
        const int q = t >> 3, u = t & 7;
        float v[4];
#pragma unroll
        for (int e = 0; e < 4; ++e) {
            const int k2 = (u << 2) + e;
            v[e] = (Sp[0][q][k2] + Sp[1][q][k2] + Sp[2][q][k2] + Sp[3][q][k2]) * 0.029462782549439483f;
        }
        float mx = fmaxf(fmaxf(v[0], v[1]), fmaxf(v[2], v[3]));
#pragma unroll
        for (int m = 1; m < 8; m <<= 1) mx = fmaxf(mx, __shfl_xor(mx, m, 64));
        float sm = 0.f;
#pragma unroll
        for (int e = 0; e < 4; ++e) { v[e] = expf(v[e] - mx); sm += v[e]; }
#pragma unroll
        for (int m = 1; m < 8; m <<= 1) sm += __shfl_xor(sm, m, 64);
        const float inv = 1.0f / sm;
#pragma unroll
        for (int e = 0; e < 4; ++e) P[(q << 5) + (u << 2) + e] = (bf16)(v[e] * inv);
    }
    __syncthreads();

    bf16x8 pa[2];
#pragma unroll
    for (int i = 0; i < 2; ++i)
        pa[i] = *(const bf16x8*)&P[(((i << 4) + l15) << 5) + (l4 << 3)];

    for (int ci = 0; ci < 3; ++ci) {
        const int cc = (ci == 0) ? 2 : (ci - 1);
        if (ci) {
            __syncthreads();
            stage_chunk(cc);
            __syncthreads();
        }
        f32x4 pacc[2][6] = {};
#pragma unroll
        for (int jn = 0; jn < 6; ++jn) {
            const int nl = w * 96 + (jn << 4) + l15;          // chunk-local col
            const bf16* tp = &ywT[nl * 44 + (l4 << 3)];       // k = l4*8 + j, contiguous
            const bf16x4 blo = *(const bf16x4*)tp;
            const bf16x4 bhi = *(const bf16x4*)(tp + 4);
            bf16x8 bv;
            bv[0] = blo[0]; bv[1] = blo[1]; bv[2] = blo[2]; bv[3] = blo[3];
            bv[4] = bhi[0]; bv[5] = bhi[1]; bv[6] = bhi[2]; bv[7] = bhi[3];
#pragma unroll
            for (int i = 0; i < 2; ++i)
                pacc[i][jn] = __builtin_amdgcn_mfma_f32_16x16x32_bf16(pa[i], bv, pacc[i][jn], 0, 0, 0);
        }
#pragma unroll
        for (int i = 0; i < 2; ++i) {
            const int mb = (i << 4) + (l4 << 2);
#pragma unroll
            for (int jn = 0; jn < 6; ++jn) {
                const int cg = cc * 384 + w * 96 + (jn << 4) + l15;
#pragma unroll
                for (int r = 0; r < 4; ++r)
                    op[(size_t)(mb + r) * 1152 + cg] = pacc[i][jn][r];
            }
        }
    }
}

// ---------------- launcher ----------------
extern "C" void kernel_launch(void* const* d_in, const int* in_sizes, int n_in,
                              void* d_out, int out_size, void* d_ws, size_t ws_size,
                              hipStream_t stream)
{
    const float* x   = (const float*)d_in[0];
    const float* W1  = (const float*)d_in[1];
    const float* b1  = (const float*)d_in[2];
    const float* g1  = (const float*)d_in[3];
    const float* be1 = (const float*)d_in[4];
    const float* W2  = (const float*)d_in[5];
    const float* b2  = (const float*)d_in[6];
    const float* g2  = (const float*)d_in[7];
    const float* be2 = (const float*)d_in[8];
    const float* W3  = (const float*)d_in[9];
    const float* b3  = (const float*)d_in[10];
    const float* g3  = (const float*)d_in[11];
    const float* be3 = (const float*)d_in[12];
    const float* Wo  = (const float*)d_in[13];
    const float* bo  = (const float*)d_in[14];
    const float* cw1 = (const float*)d_in[15];
    const float* cb1 = (const float*)d_in[16];
    const float* cw2 = (const float*)d_in[17];
    const float* cb2 = (const float*)d_in[18];
    float* out = (float*)d_out;

    const int M = 8 * 9216;  // 73728 rows
    size_t off = 0;
    auto alloc = [&](size_t nbytes) {
        void* p = (char*)d_ws + off;
        off += (nbytes + 255) & ~(size_t)255;
        return p;
    };
    bf16* Yb  = (bf16*)alloc((size_t)M * 1152 * 2);  // x-bf16 early, Y late
    bf16* Hb  = (bf16*)alloc((size_t)M * 768 * 2);   // H1; later reused as H3
    bf16* H2  = (bf16*)alloc((size_t)M * 512 * 2);
    bf16* Wt1 = (bf16*)alloc(768ull * 1152 * 2);
    bf16* Wt2 = (bf16*)alloc(512ull * 768 * 2);
    bf16* Wt3 = (bf16*)alloc(256ull * 512 * 2);
    bf16* Wto = (bf16*)alloc(1152ull * 256 * 2);
    float* ppart = (float*)alloc(8ull * 36 * 1152 * 4);
    float* sbuf  = (float*)alloc(8ull * 1152 * 4);
    bf16* Xb = Yb;
    bf16* H1 = Hb;
    bf16* H3 = Hb;

    cvt_f32_bf16_kernel<<<41472, 256, 0, stream>>>(x, Xb, (size_t)M * 1152);
    wtrans_all_kernel<<<416, 256, 0, stream>>>(W1, Wt1, W2, Wt2, W3, Wt3, Wo, Wto);

    gemm_bf16_kernel<<<6 * 576, 256, 0, stream>>>(Xb, Wt1, b1, H1, 1152, 768, 6, 1);
    ln768_kernel<<<M / 2, 256, 0, stream>>>(H1, g1, be1);
    gemm_bf16_kernel<<<4 * 576, 256, 0, stream>>>(H1, Wt2, b2, H2, 768, 512, 4, 1);
    ln512_kernel<<<M / 4, 256, 0, stream>>>(H2, g2, be2);
    gemm_bf16_kernel<<<2 * 576, 256, 0, stream>>>(H2, Wt3, b3, H3, 512, 256, 2, 1);
    ln256_kernel<<<M / 8, 256, 0, stream>>>(H3, g3, be3);
    gemm_bf16_kernel<<<9 * 576, 256, 0, stream>>>(H3, Wto, bo, Yb, 256, 1152, 9, 0);

    pool1_kernel<<<dim3(9, 36, 8), 128, 0, stream>>>(Yb, ppart);
    se_kernel<<<8, 256, 0, stream>>>(ppart, cw1, cb1, cw2, cb2, sbuf);
    attn_kernel<<<dim3(288, 8), 256, 0, stream>>>(Yb, sbuf, out);
}

// Round 8
// 983.735 us; speedup vs baseline: 1.0033x; 1.0011x over previous
//
#include <hip/hip_runtime.h>
#include <cstdint>
#include <cstddef>

typedef __bf16 bf16;
typedef __bf16 bf16x4 __attribute__((ext_vector_type(4)));
typedef __bf16 bf16x8 __attribute__((ext_vector_type(8)));
typedef float f32x4 __attribute__((ext_vector_type(4)));

__device__ __forceinline__ void gload_lds16(const bf16* g, bf16* l) {
    __builtin_amdgcn_global_load_lds((const __attribute__((address_space(1))) void*)g,
                                     (__attribute__((address_space(3))) void*)l, 16, 0, 0);
}

// ---------------- f32 -> bf16 conversion ----------------
__global__ void cvt_f32_bf16_kernel(const float* __restrict__ in, bf16* __restrict__ outp, size_t n) {
    const size_t i = ((size_t)blockIdx.x * 256 + threadIdx.x) * 8;
    if (i >= n) return;
    const float4 a = *(const float4*)(in + i);
    const float4 b = *(const float4*)(in + i + 4);
    bf16x8 o;
    o[0] = (bf16)a.x; o[1] = (bf16)a.y; o[2] = (bf16)a.z; o[3] = (bf16)a.w;
    o[4] = (bf16)b.x; o[5] = (bf16)b.y; o[6] = (bf16)b.z; o[7] = (bf16)b.w;
    *(bf16x8*)(outp + i) = o;
}

// ---------------- all 4 weight transposes in one launch ----------------
__global__ void wtrans_all_kernel(const float* __restrict__ W1, bf16* __restrict__ T1,
                                  const float* __restrict__ W2, bf16* __restrict__ T2,
                                  const float* __restrict__ W3, bf16* __restrict__ T3,
                                  const float* __restrict__ Wo, bf16* __restrict__ To)
{
    __shared__ bf16 tile[64][65];
    const int id = blockIdx.x;
    const int t = threadIdx.x;
    const float* W; bf16* T; int K, N, kb, nb;
    if (id < 216)      { W = W1; T = T1; K = 1152; N = 768;  const int r = id;       kb = r % 18; nb = r / 18; }
    else if (id < 312) { W = W2; T = T2; K = 768;  N = 512;  const int r = id - 216; kb = r % 12; nb = r / 12; }
    else if (id < 344) { W = W3; T = T3; K = 512;  N = 256;  const int r = id - 312; kb = r % 8;  nb = r / 8;  }
    else               { W = Wo; T = To; K = 256;  N = 1152; const int r = id - 344; kb = r % 4;  nb = r / 4;  }
    const int k0 = kb << 6;
    const int n0 = nb << 6;
#pragma unroll
    for (int i = 0; i < 16; ++i) {
        const int flat = i * 256 + t;
        const int r = flat >> 6;
        const int c = flat & 63;
        tile[c][r] = (bf16)W[(size_t)(k0 + r) * N + n0 + c];
    }
    __syncthreads();
#pragma unroll
    for (int i = 0; i < 16; ++i) {
        const int flat = i * 256 + t;
        const int r = flat >> 6;
        const int c = flat & 63;
        T[(size_t)(n0 + r) * K + k0 + c] = tile[r][c];
    }
}

// XCD-aware bijective swizzle (requires nwg % 8 == 0)
__device__ __forceinline__ int xcd_swz(int bid, int nwg) {
    return (bid & 7) * (nwg >> 3) + (bid >> 3);
}

// ---------------- GEMM (bf16 A): C[M][N] = A @ Bt^T + bias, optional exact GELU ----------------
__global__ void gemm_bf16_kernel(const bf16* __restrict__ A, const bf16* __restrict__ Bt,
                                 const float* __restrict__ bias, bf16* __restrict__ C,
                                 int K, int N, int nx, int do_gelu)
{
    __shared__ bf16 Alds[128 * 64];
    __shared__ bf16 Blds[128 * 64];
    const int t = threadIdx.x;
    const int w = t >> 6;
    const int l = t & 63;
    const int l15 = l & 15, l4 = l >> 4;
    const int wgid = xcd_swz(blockIdx.x, gridDim.x);
    const int mblk = wgid / nx;
    const int nblk = wgid - mblk * nx;
    const int m0 = mblk << 7;
    const int n0 = nblk << 7;
    const int wm = (w >> 1) << 6;
    const int wn = (w & 1) << 6;

    f32x4 acc[4][4] = {};

    int sr[4], sg[4];
#pragma unroll
    for (int i = 0; i < 4; ++i) {
        const int flat = i * 256 + t;
        sr[i] = flat >> 3;
        sg[i] = ((flat & 7) ^ (sr[i] & 7)) << 3;
    }

    for (int k0 = 0; k0 < K; k0 += 64) {
#pragma unroll
        for (int i = 0; i < 4; ++i) {
            gload_lds16(A + (size_t)(m0 + sr[i]) * K + (k0 + sg[i]),
                        &Alds[(size_t)(i * 256 + (w << 6)) << 3]);
            gload_lds16(Bt + (size_t)(n0 + sr[i]) * K + (k0 + sg[i]),
                        &Blds[(size_t)(i * 256 + (w << 6)) << 3]);
        }
        __syncthreads();
#pragma unroll
        for (int kk = 0; kk < 2; ++kk) {
            bf16x8 af[4], bfv[4];
#pragma unroll
            for (int i = 0; i < 4; ++i) {
                const int r = wm + (i << 4) + l15;
                const int g = (kk << 2) + l4;
                af[i] = *(const bf16x8*)&Alds[(r << 6) + ((g ^ (r & 7)) << 3)];
                const int rn = wn + (i << 4) + l15;
                bfv[i] = *(const bf16x8*)&Blds[(rn << 6) + ((g ^ (rn & 7)) << 3)];
            }
#pragma unroll
            for (int i = 0; i < 4; ++i)
#pragma unroll
                for (int j = 0; j < 4; ++j)
                    acc[i][j] = __builtin_amdgcn_mfma_f32_16x16x32_bf16(af[i], bfv[j], acc[i][j], 0, 0, 0);
        }
        __syncthreads();
    }

#pragma unroll
    for (int i = 0; i < 4; ++i) {
        const int mb = m0 + wm + (i << 4) + (l4 << 2);
#pragma unroll
        for (int j = 0; j < 4; ++j) {
            const int col = n0 + wn + (j << 4) + l15;
            const float bv = bias[col];
#pragma unroll
            for (int r = 0; r < 4; ++r) {
                float v = acc[i][j][r] + bv;
                if (do_gelu) v = 0.5f * v * (1.0f + erff(v * 0.70710678118654752f));
                C[(size_t)(mb + r) * N + col] = (bf16)v;
            }
        }
    }
}

// ---------------- LayerNorms ----------------
__global__ void ln768_kernel(bf16* __restrict__ H, const float* __restrict__ g,
                             const float* __restrict__ be)
{
    const int t = threadIdx.x;
    const int rloc = t >> 7;
    const int u = t & 127;
    bf16* hp = H + ((size_t)blockIdx.x * 2 + rloc) * 768;
    float v[8];
    float s1 = 0.f, s2 = 0.f;
    if (u < 96) {
        const bf16x8 hv = *(const bf16x8*)(hp + u * 8);
#pragma unroll
        for (int e = 0; e < 8; ++e) { v[e] = (float)hv[e]; s1 += v[e]; s2 += v[e] * v[e]; }
    }
#pragma unroll
    for (int m = 1; m < 64; m <<= 1) { s1 += __shfl_xor(s1, m, 64); s2 += __shfl_xor(s2, m, 64); }
    __shared__ float red[8];
    const int w = t >> 6;
    if ((t & 63) == 0) { red[w] = s1; red[w + 4] = s2; }
    __syncthreads();
    const int wb = rloc << 1;
    s1 = red[wb] + red[wb + 1];
    s2 = red[wb + 4] + red[wb + 5];
    const float mu = s1 * (1.0f / 768.0f);
    const float rstd = rsqrtf(s2 * (1.0f / 768.0f) - mu * mu + 1e-5f);
    if (u < 96) {
        const float4 g0 = *(const float4*)(g + u * 8);
        const float4 g1 = *(const float4*)(g + u * 8 + 4);
        const float4 b0 = *(const float4*)(be + u * 8);
        const float4 b1 = *(const float4*)(be + u * 8 + 4);
        bf16x8 o;
        o[0] = (bf16)((v[0] - mu) * rstd * g0.x + b0.x);
        o[1] = (bf16)((v[1] - mu) * rstd * g0.y + b0.y);
        o[2] = (bf16)((v[2] - mu) * rstd * g0.z + b0.z);
        o[3] = (bf16)((v[3] - mu) * rstd * g0.w + b0.w);
        o[4] = (bf16)((v[4] - mu) * rstd * g1.x + b1.x);
        o[5] = (bf16)((v[5] - mu) * rstd * g1.y + b1.y);
        o[6] = (bf16)((v[6] - mu) * rstd * g1.z + b1.z);
        o[7] = (bf16)((v[7] - mu) * rstd * g1.w + b1.w);
        *(bf16x8*)(hp + u * 8) = o;
    }
}

__global__ void ln512_kernel(bf16* __restrict__ H, const float* __restrict__ g,
                             const float* __restrict__ be)
{
    const int t = threadIdx.x;
    const int w = t >> 6, l = t & 63;
    bf16* hp = H + ((size_t)blockIdx.x * 4 + w) * 512;
    const bf16x8 hv = *(const bf16x8*)(hp + l * 8);
    float v[8];
    float s1 = 0.f, s2 = 0.f;
#pragma unroll
    for (int e = 0; e < 8; ++e) { v[e] = (float)hv[e]; s1 += v[e]; s2 += v[e] * v[e]; }
#pragma unroll
    for (int m = 1; m < 64; m <<= 1) { s1 += __shfl_xor(s1, m, 64); s2 += __shfl_xor(s2, m, 64); }
    const float mu = s1 * (1.0f / 512.0f);
    const float rstd = rsqrtf(s2 * (1.0f / 512.0f) - mu * mu + 1e-5f);
    const float4 g0 = *(const float4*)(g + l * 8);
    const float4 g1 = *(const float4*)(g + l * 8 + 4);
    const float4 b0 = *(const float4*)(be + l * 8);
    const float4 b1 = *(const float4*)(be + l * 8 + 4);
    bf16x8 o;
    o[0] = (bf16)((v[0] - mu) * rstd * g0.x + b0.x);
    o[1] = (bf16)((v[1] - mu) * rstd * g0.y + b0.y);
    o[2] = (bf16)((v[2] - mu) * rstd * g0.z + b0.z);
    o[3] = (bf16)((v[3] - mu) * rstd * g0.w + b0.w);
    o[4] = (bf16)((v[4] - mu) * rstd * g1.x + b1.x);
    o[5] = (bf16)((v[5] - mu) * rstd * g1.y + b1.y);
    o[6] = (bf16)((v[6] - mu) * rstd * g1.z + b1.z);
    o[7] = (bf16)((v[7] - mu) * rstd * g1.w + b1.w);
    *(bf16x8*)(hp + l * 8) = o;
}

__global__ void ln256_kernel(bf16* __restrict__ H, const float* __restrict__ g,
                             const float* __restrict__ be)
{
    const int t = threadIdx.x;
    const int rloc = t >> 5, l = t & 31;
    bf16* hp = H + ((size_t)blockIdx.x * 8 + rloc) * 256;
    const bf16x8 hv = *(const bf16x8*)(hp + l * 8);
    float v[8];
    float s1 = 0.f, s2 = 0.f;
#pragma unroll
    for (int e = 0; e < 8; ++e) { v[e] = (float)hv[e]; s1 += v[e]; s2 += v[e] * v[e]; }
#pragma unroll
    for (int m = 1; m < 32; m <<= 1) { s1 += __shfl_xor(s1, m, 64); s2 += __shfl_xor(s2, m, 64); }
    const float mu = s1 * (1.0f / 256.0f);
    const float rstd = rsqrtf(s2 * (1.0f / 256.0f) - mu * mu + 1e-5f);
    const float4 g0 = *(const float4*)(g + l * 8);
    const float4 g1 = *(const float4*)(g + l * 8 + 4);
    const float4 b0 = *(const float4*)(be + l * 8);
    const float4 b1 = *(const float4*)(be + l * 8 + 4);
    bf16x8 o;
    o[0] = (bf16)((v[0] - mu) * rstd * g0.x + b0.x);
    o[1] = (bf16)((v[1] - mu) * rstd * g0.y + b0.y);
    o[2] = (bf16)((v[2] - mu) * rstd * g0.z + b0.z);
    o[3] = (bf16)((v[3] - mu) * rstd * g0.w + b0.w);
    o[4] = (bf16)((v[4] - mu) * rstd * g1.x + b1.x);
    o[5] = (bf16)((v[5] - mu) * rstd * g1.y + b1.y);
    o[6] = (bf16)((v[6] - mu) * rstd * g1.z + b1.z);
    o[7] = (bf16)((v[7] - mu) * rstd * g1.w + b1.w);
    *(bf16x8*)(hp + l * 8) = o;
}

// ---------------- pooled mean (pass 2 fused into se) ----------------
__global__ void pool1_kernel(const bf16* __restrict__ Y, float* __restrict__ ppart) {
    const int c = blockIdx.x * 128 + threadIdx.x;
    const int nc = blockIdx.y;
    const int b = blockIdx.z;
    const bf16* yp = Y + ((size_t)b * 9216 + (size_t)nc * 256) * 1152 + c;
    float s = 0.f;
#pragma unroll 4
    for (int i = 0; i < 256; ++i) s += (float)yp[(size_t)i * 1152];
    ppart[((size_t)b * 36 + nc) * 1152 + c] = s;
}

// ---------------- SE MLP ----------------
__global__ void se_kernel(const float* __restrict__ ppart,
                          const float* __restrict__ w1, const float* __restrict__ b1,
                          const float* __restrict__ w2, const float* __restrict__ b2,
                          float* __restrict__ sbuf)
{
    const int b = blockIdx.x, t = threadIdx.x;
    __shared__ float p[1152];
    __shared__ float t1[144];
    for (int c = t; c < 1152; c += 256) {
        float s = 0.f;
#pragma unroll
        for (int j = 0; j < 36; ++j) s += ppart[((size_t)b * 36 + j) * 1152 + c];
        p[c] = s * (1.0f / 9216.0f);
    }
    __syncthreads();
    if (t < 144) {
        float a = b1[t];
        for (int k = 0; k < 1152; ++k) a += p[k] * w1[k * 144 + t];
        t1[t] = a > 0.f ? a : 0.f;
    }
    __syncthreads();
    for (int c = t; c < 1152; c += 256) {
        float a = b2[c];
#pragma unroll 8
        for (int k = 0; k < 144; ++k) a += t1[k] * w2[k * 1152 + c];
        sbuf[b * 1152 + c] = 1.0f / (1.0f + expf(-a));
    }
}

// ---------------- windowed self-attention ----------------
// yw: row-major chunk (QK^T operands, XOR-swizzled 16B groups)
// ywT: transposed chunk [col][k], rows padded to 44 elems (88B: b64-aligned reads,
//      write banks spread) -> PV B-frags become 2x ds_read_b64 instead of 48 scalar u16 gathers.
__device__ __forceinline__ int fswz(int r) { return (r & 7) ^ ((r >> 3) & 3); }

__global__ void attn_kernel(const bf16* __restrict__ Y, const float* __restrict__ sbuf,
                            float* __restrict__ out)
{
    __shared__ bf16 yw[32 * 384];
    __shared__ bf16 ywT[384 * 44];
    __shared__ float Sp[4][32][33];
    __shared__ bf16 P[32 * 32];

    const int t = threadIdx.x;
    const int w = t >> 6, l = t & 63;
    const int l15 = l & 15, l4 = l >> 4;
    const int wdx = blockIdx.x, b = blockIdx.y;

    const bf16* Yp = Y + ((size_t)b * 9216 + (size_t)wdx * 32) * 1152;
    const float* sv = sbuf + b * 1152;
    float* op = out + ((size_t)b * 9216 + (size_t)wdx * 32) * 1152;

    auto stage_chunk = [&](int cc) {
#pragma unroll
        for (int i = 0; i < 6; ++i) {
            const int flat = i * 256 + t;
            const int r = flat / 48;
            const int gg = flat - r * 48;
            const int c0 = cc * 384 + gg * 8;
            const bf16x8 yv = *(const bf16x8*)(Yp + (size_t)r * 1152 + c0);
            const float4 sa = *(const float4*)(sv + c0);
            const float4 sb = *(const float4*)(sv + c0 + 4);
            bf16x8 ov;
            ov[0] = (bf16)((float)yv[0] * sa.x);
            ov[1] = (bf16)((float)yv[1] * sa.y);
            ov[2] = (bf16)((float)yv[2] * sa.z);
            ov[3] = (bf16)((float)yv[3] * sa.w);
            ov[4] = (bf16)((float)yv[4] * sb.x);
            ov[5] = (bf16)((float)yv[5] * sb.y);
            ov[6] = (bf16)((float)yv[6] * sb.z);
            ov[7] = (bf16)((float)yv[7] * sb.w);
            *(bf16x8*)&yw[((r * 48) + (gg ^ fswz(r))) << 3] = ov;
            // transposed copy (chunk-local col = gg*8+e, row k = r)
#pragma unroll
            for (int e = 0; e < 8; ++e)
                ywT[(gg * 8 + e) * 44 + r] = ov[e];
        }
    };

    f32x4 acc[2][2] = {};
    for (int cc = 0; cc < 3; ++cc) {
        if (cc) __syncthreads();
        stage_chunk(cc);
        __syncthreads();
#pragma unroll
        for (int kkl = 0; kkl < 3; ++kkl) {
            const int g = ((w * 3 + kkl) << 2) + l4;
            bf16x8 af[2];
#pragma unroll
            for (int i = 0; i < 2; ++i) {
                const int r = (i << 4) + l15;
                af[i] = *(const bf16x8*)&yw[((r * 48) + (g ^ fswz(r))) << 3];
            }
#pragma unroll
            for (int i = 0; i < 2; ++i)
#pragma unroll
                for (int j = 0; j < 2; ++j)
                    acc[i][j] = __builtin_amdgcn_mfma_f32_16x16x32_bf16(af[i], af[j], acc[i][j], 0, 0, 0);
        }
    }
#pragma unroll
    for (int i = 0; i < 2; ++i)
#pragma unroll
        for (int j = 0; j < 2; ++j)
#pragma unroll
            for (int r = 0; r < 4; ++r)
                Sp[w][(i << 4) + (l4 << 2) + r][(j << 4) + l15] = acc[i][j][r];
    __syncthreads();

    {
        const int q = t >> 3, u = t & 7;
        float v[4];
#pragma unroll
        for (int e = 0; e < 4; ++e) {
            const int k2 = (u << 2) + e;
            v[e] = (Sp[0][q][k2] + Sp[1][q][k2] + Sp[2][q][k2] + Sp[3][q][k2]) * 0.029462782549439483f;
        }
        float mx = fmaxf(fmaxf(v[0], v[1]), fmaxf(v[2], v[3]));
#pragma unroll
        for (int m = 1; m < 8; m <<= 1) mx = fmaxf(mx, __shfl_xor(mx, m, 64));
        float sm = 0.f;
#pragma unroll
        for (int e = 0; e < 4; ++e) { v[e] = expf(v[e] - mx); sm += v[e]; }
#pragma unroll
        for (int m = 1; m < 8; m <<= 1) sm += __shfl_xor(sm, m, 64);
        const float inv = 1.0f / sm;
#pragma unroll
        for (int e = 0; e < 4; ++e) P[(q << 5) + (u << 2) + e] = (bf16)(v[e] * inv);
    }
    __syncthreads();

    bf16x8 pa[2];
#pragma unroll
    for (int i = 0; i < 2; ++i)
        pa[i] = *(const bf16x8*)&P[(((i << 4) + l15) << 5) + (l4 << 3)];

    for (int ci = 0; ci < 3; ++ci) {
        const int cc = (ci == 0) ? 2 : (ci - 1);
        if (ci) {
            __syncthreads();
            stage_chunk(cc);
            __syncthreads();
        }
        f32x4 pacc[2][6] = {};
#pragma unroll
        for (int jn = 0; jn < 6; ++jn) {
            const int nl = w * 96 + (jn << 4) + l15;          // chunk-local col
            const bf16* tp = &ywT[nl * 44 + (l4 << 3)];       // k = l4*8 + j, contiguous
            const bf16x4 blo = *(const bf16x4*)tp;
            const bf16x4 bhi = *(const bf16x4*)(tp + 4);
            bf16x8 bv;
            bv[0] = blo[0]; bv[1] = blo[1]; bv[2] = blo[2]; bv[3] = blo[3];
            bv[4] = bhi[0]; bv[5] = bhi[1]; bv[6] = bhi[2]; bv[7] = bhi[3];
#pragma unroll
            for (int i = 0; i < 2; ++i)
                pacc[i][jn] = __builtin_amdgcn_mfma_f32_16x16x32_bf16(pa[i], bv, pacc[i][jn], 0, 0, 0);
        }
#pragma unroll
        for (int i = 0; i < 2; ++i) {
            const int mb = (i << 4) + (l4 << 2);
#pragma unroll
            for (int jn = 0; jn < 6; ++jn) {
                const int cg = cc * 384 + w * 96 + (jn << 4) + l15;
#pragma unroll
                for (int r = 0; r < 4; ++r)
                    op[(size_t)(mb + r) * 1152 + cg] = pacc[i][jn][r];
            }
        }
    }
}

// ---------------- launcher ----------------
extern "C" void kernel_launch(void* const* d_in, const int* in_sizes, int n_in,
                              void* d_out, int out_size, void* d_ws, size_t ws_size,
                              hipStream_t stream)
{
    const float* x   = (const float*)d_in[0];
    const float* W1  = (const float*)d_in[1];
    const float* b1  = (const float*)d_in[2];
    const float* g1  = (const float*)d_in[3];
    const float* be1 = (const float*)d_in[4];
    const float* W2  = (const float*)d_in[5];
    const float* b2  = (const float*)d_in[6];
    const float* g2  = (const float*)d_in[7];
    const float* be2 = (const float*)d_in[8];
    const float* W3  = (const float*)d_in[9];
    const float* b3  = (const float*)d_in[10];
    const float* g3  = (const float*)d_in[11];
    const float* be3 = (const float*)d_in[12];
    const float* Wo  = (const float*)d_in[13];
    const float* bo  = (const float*)d_in[14];
    const float* cw1 = (const float*)d_in[15];
    const float* cb1 = (const float*)d_in[16];
    const float* cw2 = (const float*)d_in[17];
    const float* cb2 = (const float*)d_in[18];
    float* out = (float*)d_out;

    const int M = 8 * 9216;  // 73728 rows
    size_t off = 0;
    auto alloc = [&](size_t nbytes) {
        void* p = (char*)d_ws + off;
        off += (nbytes + 255) & ~(size_t)255;
        return p;
    };
    bf16* Yb  = (bf16*)alloc((size_t)M * 1152 * 2);  // x-bf16 early, Y late
    bf16* Hb  = (bf16*)alloc((size_t)M * 768 * 2);   // H1; later reused as H3
    bf16* H2  = (bf16*)alloc((size_t)M * 512 * 2);
    bf16* Wt1 = (bf16*)alloc(768ull * 1152 * 2);
    bf16* Wt2 = (bf16*)alloc(512ull * 768 * 2);
    bf16* Wt3 = (bf16*)alloc(256ull * 512 * 2);
    bf16* Wto = (bf16*)alloc(1152ull * 256 * 2);
    float* ppart = (float*)alloc(8ull * 36 * 1152 * 4);
    float* sbuf  = (float*)alloc(8ull * 1152 * 4);
    bf16* Xb = Yb;
    bf16* H1 = Hb;
    bf16* H3 = Hb;

    cvt_f32_bf16_kernel<<<41472, 256, 0, stream>>>(x, Xb, (size_t)M * 1152);
    wtrans_all_kernel<<<416, 256, 0, stream>>>(W1, Wt1, W2, Wt2, W3, Wt3, Wo, Wto);

    gemm_bf16_kernel<<<6 * 576, 256, 0, stream>>>(Xb, Wt1, b1, H1, 1152, 768, 6, 1);
    ln768_kernel<<<M / 2, 256, 0, stream>>>(H1, g1, be1);
    gemm_bf16_kernel<<<4 * 576, 256, 0, stream>>>(H1, Wt2, b2, H2, 768, 512, 4, 1);
    ln512_kernel<<<M / 4, 256, 0, stream>>>(H2, g2, be2);
    gemm_bf16_kernel<<<2 * 576, 256, 0, stream>>>(H2, Wt3, b3, H3, 512, 256, 2, 1);
    ln256_kernel<<<M / 8, 256, 0, stream>>>(H3, g3, be3);
    gemm_bf16_kernel<<<9 * 576, 256, 0, stream>>>(H3, Wto, bo, Yb, 256, 1152, 9, 0);

    pool1_kernel<<<dim3(9, 36, 8), 128, 0, stream>>>(Yb, ppart);
    se_kernel<<<8, 256, 0, stream>>>(ppart, cw1, cb1, cw2, cb2, sbuf);
    attn_kernel<<<dim3(288, 8), 256, 0, stream>>>(Yb, sbuf, out);
}

// Round 9
// 884.057 us; speedup vs baseline: 1.1164x; 1.1128x over previous
//
#include <hip/hip_runtime.h>
#include <cstdint>
#include <cstddef>

typedef __bf16 bf16;
typedef __bf16 bf16x8 __attribute__((ext_vector_type(8)));
typedef float f32x4 __attribute__((ext_vector_type(4)));

__device__ __forceinline__ void gload_lds16(const bf16* g, bf16* l) {
    __builtin_amdgcn_global_load_lds((const __attribute__((address_space(1))) void*)g,
                                     (__attribute__((address_space(3))) void*)l, 16, 0, 0);
}

// ---------------- f32 -> bf16 conversion ----------------
__global__ void cvt_f32_bf16_kernel(const float* __restrict__ in, bf16* __restrict__ outp, size_t n) {
    const size_t i = ((size_t)blockIdx.x * 256 + threadIdx.x) * 8;
    if (i >= n) return;
    const float4 a = *(const float4*)(in + i);
    const float4 b = *(const float4*)(in + i + 4);
    bf16x8 o;
    o[0] = (bf16)a.x; o[1] = (bf16)a.y; o[2] = (bf16)a.z; o[3] = (bf16)a.w;
    o[4] = (bf16)b.x; o[5] = (bf16)b.y; o[6] = (bf16)b.z; o[7] = (bf16)b.w;
    *(bf16x8*)(outp + i) = o;
}

// ---------------- all 4 weight transposes in one launch ----------------
__global__ void wtrans_all_kernel(const float* __restrict__ W1, bf16* __restrict__ T1,
                                  const float* __restrict__ W2, bf16* __restrict__ T2,
                                  const float* __restrict__ W3, bf16* __restrict__ T3,
                                  const float* __restrict__ Wo, bf16* __restrict__ To)
{
    __shared__ bf16 tile[64][65];
    const int id = blockIdx.x;
    const int t = threadIdx.x;
    const float* W; bf16* T; int K, N, kb, nb;
    if (id < 216)      { W = W1; T = T1; K = 1152; N = 768;  const int r = id;       kb = r % 18; nb = r / 18; }
    else if (id < 312) { W = W2; T = T2; K = 768;  N = 512;  const int r = id - 216; kb = r % 12; nb = r / 12; }
    else if (id < 344) { W = W3; T = T3; K = 512;  N = 256;  const int r = id - 312; kb = r % 8;  nb = r / 8;  }
    else               { W = Wo; T = To; K = 256;  N = 1152; const int r = id - 344; kb = r % 4;  nb = r / 4;  }
    const int k0 = kb << 6;
    const int n0 = nb << 6;
#pragma unroll
    for (int i = 0; i < 16; ++i) {
        const int flat = i * 256 + t;
        const int r = flat >> 6;
        const int c = flat & 63;
        tile[c][r] = (bf16)W[(size_t)(k0 + r) * N + n0 + c];
    }
    __syncthreads();
#pragma unroll
    for (int i = 0; i < 16; ++i) {
        const int flat = i * 256 + t;
        const int r = flat >> 6;
        const int c = flat & 63;
        T[(size_t)(n0 + r) * K + k0 + c] = tile[r][c];
    }
}

// XCD-aware bijective swizzle (requires nwg % 8 == 0)
__device__ __forceinline__ int xcd_swz(int bid, int nwg) {
    return (bid & 7) * (nwg >> 3) + (bid >> 3);
}

// ---------------- GEMM (bf16 A): C[M][N] = A @ Bt^T + bias, optional exact GELU ----------------
__global__ void gemm_bf16_kernel(const bf16* __restrict__ A, const bf16* __restrict__ Bt,
                                 const float* __restrict__ bias, bf16* __restrict__ C,
                                 int K, int N, int nx, int do_gelu)
{
    __shared__ bf16 Alds[128 * 64];
    __shared__ bf16 Blds[128 * 64];
    const int t = threadIdx.x;
    const int w = t >> 6;
    const int l = t & 63;
    const int l15 = l & 15, l4 = l >> 4;
    const int wgid = xcd_swz(blockIdx.x, gridDim.x);
    const int mblk = wgid / nx;
    const int nblk = wgid - mblk * nx;
    const int m0 = mblk << 7;
    const int n0 = nblk << 7;
    const int wm = (w >> 1) << 6;
    const int wn = (w & 1) << 6;

    f32x4 acc[4][4] = {};

    int sr[4], sg[4];
#pragma unroll
    for (int i = 0; i < 4; ++i) {
        const int flat = i * 256 + t;
        sr[i] = flat >> 3;
        sg[i] = ((flat & 7) ^ (sr[i] & 7)) << 3;
    }

    for (int k0 = 0; k0 < K; k0 += 64) {
#pragma unroll
        for (int i = 0; i < 4; ++i) {
            gload_lds16(A + (size_t)(m0 + sr[i]) * K + (k0 + sg[i]),
                        &Alds[(size_t)(i * 256 + (w << 6)) << 3]);
            gload_lds16(Bt + (size_t)(n0 + sr[i]) * K + (k0 + sg[i]),
                        &Blds[(size_t)(i * 256 + (w << 6)) << 3]);
        }
        __syncthreads();
#pragma unroll
        for (int kk = 0; kk < 2; ++kk) {
            bf16x8 af[4], bfv[4];
#pragma unroll
            for (int i = 0; i < 4; ++i) {
                const int r = wm + (i << 4) + l15;
                const int g = (kk << 2) + l4;
                af[i] = *(const bf16x8*)&Alds[(r << 6) + ((g ^ (r & 7)) << 3)];
                const int rn = wn + (i << 4) + l15;
                bfv[i] = *(const bf16x8*)&Blds[(rn << 6) + ((g ^ (rn & 7)) << 3)];
            }
#pragma unroll
            for (int i = 0; i < 4; ++i)
#pragma unroll
                for (int j = 0; j < 4; ++j)
                    acc[i][j] = __builtin_amdgcn_mfma_f32_16x16x32_bf16(af[i], bfv[j], acc[i][j], 0, 0, 0);
        }
        __syncthreads();
    }

#pragma unroll
    for (int i = 0; i < 4; ++i) {
        const int mb = m0 + wm + (i << 4) + (l4 << 2);
#pragma unroll
        for (int j = 0; j < 4; ++j) {
            const int col = n0 + wn + (j << 4) + l15;
            const float bv = bias[col];
#pragma unroll
            for (int r = 0; r < 4; ++r) {
                float v = acc[i][j][r] + bv;
                if (do_gelu) v = 0.5f * v * (1.0f + erff(v * 0.70710678118654752f));
                C[(size_t)(mb + r) * N + col] = (bf16)v;
            }
        }
    }
}

// ---------------- LayerNorms ----------------
__global__ void ln768_kernel(bf16* __restrict__ H, const float* __restrict__ g,
                             const float* __restrict__ be)
{
    const int t = threadIdx.x;
    const int rloc = t >> 7;
    const int u = t & 127;
    bf16* hp = H + ((size_t)blockIdx.x * 2 + rloc) * 768;
    float v[8];
    float s1 = 0.f, s2 = 0.f;
    if (u < 96) {
        const bf16x8 hv = *(const bf16x8*)(hp + u * 8);
#pragma unroll
        for (int e = 0; e < 8; ++e) { v[e] = (float)hv[e]; s1 += v[e]; s2 += v[e] * v[e]; }
    }
#pragma unroll
    for (int m = 1; m < 64; m <<= 1) { s1 += __shfl_xor(s1, m, 64); s2 += __shfl_xor(s2, m, 64); }
    __shared__ float red[8];
    const int w = t >> 6;
    if ((t & 63) == 0) { red[w] = s1; red[w + 4] = s2; }
    __syncthreads();
    const int wb = rloc << 1;
    s1 = red[wb] + red[wb + 1];
    s2 = red[wb + 4] + red[wb + 5];
    const float mu = s1 * (1.0f / 768.0f);
    const float rstd = rsqrtf(s2 * (1.0f / 768.0f) - mu * mu + 1e-5f);
    if (u < 96) {
        const float4 g0 = *(const float4*)(g + u * 8);
        const float4 g1 = *(const float4*)(g + u * 8 + 4);
        const float4 b0 = *(const float4*)(be + u * 8);
        const float4 b1 = *(const float4*)(be + u * 8 + 4);
        bf16x8 o;
        o[0] = (bf16)((v[0] - mu) * rstd * g0.x + b0.x);
        o[1] = (bf16)((v[1] - mu) * rstd * g0.y + b0.y);
        o[2] = (bf16)((v[2] - mu) * rstd * g0.z + b0.z);
        o[3] = (bf16)((v[3] - mu) * rstd * g0.w + b0.w);
        o[4] = (bf16)((v[4] - mu) * rstd * g1.x + b1.x);
        o[5] = (bf16)((v[5] - mu) * rstd * g1.y + b1.y);
        o[6] = (bf16)((v[6] - mu) * rstd * g1.z + b1.z);
        o[7] = (bf16)((v[7] - mu) * rstd * g1.w + b1.w);
        *(bf16x8*)(hp + u * 8) = o;
    }
}

__global__ void ln512_kernel(bf16* __restrict__ H, const float* __restrict__ g,
                             const float* __restrict__ be)
{
    const int t = threadIdx.x;
    const int w = t >> 6, l = t & 63;
    bf16* hp = H + ((size_t)blockIdx.x * 4 + w) * 512;
    const bf16x8 hv = *(const bf16x8*)(hp + l * 8);
    float v[8];
    float s1 = 0.f, s2 = 0.f;
#pragma unroll
    for (int e = 0; e < 8; ++e) { v[e] = (float)hv[e]; s1 += v[e]; s2 += v[e] * v[e]; }
#pragma unroll
    for (int m = 1; m < 64; m <<= 1) { s1 += __shfl_xor(s1, m, 64); s2 += __shfl_xor(s2, m, 64); }
    const float mu = s1 * (1.0f / 512.0f);
    const float rstd = rsqrtf(s2 * (1.0f / 512.0f) - mu * mu + 1e-5f);
    const float4 g0 = *(const float4*)(g + l * 8);
    const float4 g1 = *(const float4*)(g + l * 8 + 4);
    const float4 b0 = *(const float4*)(be + l * 8);
    const float4 b1 = *(const float4*)(be + l * 8 + 4);
    bf16x8 o;
    o[0] = (bf16)((v[0] - mu) * rstd * g0.x + b0.x);
    o[1] = (bf16)((v[1] - mu) * rstd * g0.y + b0.y);
    o[2] = (bf16)((v[2] - mu) * rstd * g0.z + b0.z);
    o[3] = (bf16)((v[3] - mu) * rstd * g0.w + b0.w);
    o[4] = (bf16)((v[4] - mu) * rstd * g1.x + b1.x);
    o[5] = (bf16)((v[5] - mu) * rstd * g1.y + b1.y);
    o[6] = (bf16)((v[6] - mu) * rstd * g1.z + b1.z);
    o[7] = (bf16)((v[7] - mu) * rstd * g1.w + b1.w);
    *(bf16x8*)(hp + l * 8) = o;
}

__global__ void ln256_kernel(bf16* __restrict__ H, const float* __restrict__ g,
                             const float* __restrict__ be)
{
    const int t = threadIdx.x;
    const int rloc = t >> 5, l = t & 31;
    bf16* hp = H + ((size_t)blockIdx.x * 8 + rloc) * 256;
    const bf16x8 hv = *(const bf16x8*)(hp + l * 8);
    float v[8];
    float s1 = 0.f, s2 = 0.f;
#pragma unroll
    for (int e = 0; e < 8; ++e) { v[e] = (float)hv[e]; s1 += v[e]; s2 += v[e] * v[e]; }
#pragma unroll
    for (int m = 1; m < 32; m <<= 1) { s1 += __shfl_xor(s1, m, 64); s2 += __shfl_xor(s2, m, 64); }
    const float mu = s1 * (1.0f / 256.0f);
    const float rstd = rsqrtf(s2 * (1.0f / 256.0f) - mu * mu + 1e-5f);
    const float4 g0 = *(const float4*)(g + l * 8);
    const float4 g1 = *(const float4*)(g + l * 8 + 4);
    const float4 b0 = *(const float4*)(be + l * 8);
    const float4 b1 = *(const float4*)(be + l * 8 + 4);
    bf16x8 o;
    o[0] = (bf16)((v[0] - mu) * rstd * g0.x + b0.x);
    o[1] = (bf16)((v[1] - mu) * rstd * g0.y + b0.y);
    o[2] = (bf16)((v[2] - mu) * rstd * g0.z + b0.z);
    o[3] = (bf16)((v[3] - mu) * rstd * g0.w + b0.w);
    o[4] = (bf16)((v[4] - mu) * rstd * g1.x + b1.x);
    o[5] = (bf16)((v[5] - mu) * rstd * g1.y + b1.y);
    o[6] = (bf16)((v[6] - mu) * rstd * g1.z + b1.z);
    o[7] = (bf16)((v[7] - mu) * rstd * g1.w + b1.w);
    *(bf16x8*)(hp + l * 8) = o;
}

// ---------------- pooled mean (pass 2 fused into se) ----------------
__global__ void pool1_kernel(const bf16* __restrict__ Y, float* __restrict__ ppart) {
    const int c = blockIdx.x * 128 + threadIdx.x;
    const int nc = blockIdx.y;
    const int b = blockIdx.z;
    const bf16* yp = Y + ((size_t)b * 9216 + (size_t)nc * 256) * 1152 + c;
    float s = 0.f;
#pragma unroll 4
    for (int i = 0; i < 256; ++i) s += (float)yp[(size_t)i * 1152];
    ppart[((size_t)b * 36 + nc) * 1152 + c] = s;
}

// ---------------- SE MLP ----------------
__global__ void se_kernel(const float* __restrict__ ppart,
                          const float* __restrict__ w1, const float* __restrict__ b1,
                          const float* __restrict__ w2, const float* __restrict__ b2,
                          float* __restrict__ sbuf)
{
    const int b = blockIdx.x, t = threadIdx.x;
    __shared__ float p[1152];
    __shared__ float t1[144];
    for (int c = t; c < 1152; c += 256) {
        float s = 0.f;
#pragma unroll
        for (int j = 0; j < 36; ++j) s += ppart[((size_t)b * 36 + j) * 1152 + c];
        p[c] = s * (1.0f / 9216.0f);
    }
    __syncthreads();
    if (t < 144) {
        float a = b1[t];
        for (int k = 0; k < 1152; ++k) a += p[k] * w1[k * 144 + t];
        t1[t] = a > 0.f ? a : 0.f;
    }
    __syncthreads();
    for (int c = t; c < 1152; c += 256) {
        float a = b2[c];
#pragma unroll 8
        for (int k = 0; k < 144; ++k) a += t1[k] * w2[k * 1152 + c];
        sbuf[b * 1152 + c] = 1.0f / (1.0f + expf(-a));
    }
}

// ---------------- windowed self-attention ----------------
// yw row-major XOR-swizzled (QK^T + PV gather); output staged in LDS (stride-388 f32,
// 2-way-free banks) then written as full 128B lines -> kills write amplification.
__device__ __forceinline__ int fswz(int r) { return (r & 7) ^ ((r >> 3) & 3); }

#define OSTG_STRIDE 388

__global__ void attn_kernel(const bf16* __restrict__ Y, const float* __restrict__ sbuf,
                            float* __restrict__ out)
{
    // 24576 (yw) + 49664 (ostg/Sp union) + 2048 (P) = 76288 B -> 2 blocks/CU
    __shared__ __align__(16) char smem[24576 + 49664 + 2048];
    bf16*  yw   = (bf16*)smem;                       // [32][384] swizzled
    float* SpF  = (float*)(smem + 24576);            // [4][32][33] (score phase only)
    float* ostg = (float*)(smem + 24576);            // [32][388]  (PV phase only)
    bf16*  P    = (bf16*)(smem + 24576 + 49664);     // [32][32]

    const int t = threadIdx.x;
    const int w = t >> 6, l = t & 63;
    const int l15 = l & 15, l4 = l >> 4;
    const int wdx = blockIdx.x, b = blockIdx.y;

    const bf16* Yp = Y + ((size_t)b * 9216 + (size_t)wdx * 32) * 1152;
    const float* sv = sbuf + b * 1152;
    float* op = out + ((size_t)b * 9216 + (size_t)wdx * 32) * 1152;

    auto stage_chunk = [&](int cc) {
#pragma unroll
        for (int i = 0; i < 6; ++i) {
            const int flat = i * 256 + t;
            const int r = flat / 48;
            const int gg = flat - r * 48;
            const int c0 = cc * 384 + gg * 8;
            const bf16x8 yv = *(const bf16x8*)(Yp + (size_t)r * 1152 + c0);
            const float4 sa = *(const float4*)(sv + c0);
            const float4 sb = *(const float4*)(sv + c0 + 4);
            bf16x8 ov;
            ov[0] = (bf16)((float)yv[0] * sa.x);
            ov[1] = (bf16)((float)yv[1] * sa.y);
            ov[2] = (bf16)((float)yv[2] * sa.z);
            ov[3] = (bf16)((float)yv[3] * sa.w);
            ov[4] = (bf16)((float)yv[4] * sb.x);
            ov[5] = (bf16)((float)yv[5] * sb.y);
            ov[6] = (bf16)((float)yv[6] * sb.z);
            ov[7] = (bf16)((float)yv[7] * sb.w);
            *(bf16x8*)&yw[((r * 48) + (gg ^ fswz(r))) << 3] = ov;
        }
    };

    f32x4 acc[2][2] = {};
    for (int cc = 0; cc < 3; ++cc) {
        if (cc) __syncthreads();
        stage_chunk(cc);
        __syncthreads();
#pragma unroll
        for (int kkl = 0; kkl < 3; ++kkl) {
            const int g = ((w * 3 + kkl) << 2) + l4;
            bf16x8 af[2];
#pragma unroll
            for (int i = 0; i < 2; ++i) {
                const int r = (i << 4) + l15;
                af[i] = *(const bf16x8*)&yw[((r * 48) + (g ^ fswz(r))) << 3];
            }
#pragma unroll
            for (int i = 0; i < 2; ++i)
#pragma unroll
                for (int j = 0; j < 2; ++j)
                    acc[i][j] = __builtin_amdgcn_mfma_f32_16x16x32_bf16(af[i], af[j], acc[i][j], 0, 0, 0);
        }
    }
#pragma unroll
    for (int i = 0; i < 2; ++i)
#pragma unroll
        for (int j = 0; j < 2; ++j)
#pragma unroll
            for (int r = 0; r < 4; ++r)
                SpF[w * 1056 + ((i << 4) + (l4 << 2) + r) * 33 + (j << 4) + l15] = acc[i][j][r];
    __syncthreads();

    {
        const int q = t >> 3, u = t & 7;
        float v[4];
#pragma unroll
        for (int e = 0; e < 4; ++e) {
            const int k2 = (u << 2) + e;
            v[e] = (SpF[q * 33 + k2] + SpF[1056 + q * 33 + k2] +
                    SpF[2112 + q * 33 + k2] + SpF[3168 + q * 33 + k2]) * 0.029462782549439483f;
        }
        float mx = fmaxf(fmaxf(v[0], v[1]), fmaxf(v[2], v[3]));
#pragma unroll
        for (int m = 1; m < 8; m <<= 1) mx = fmaxf(mx, __shfl_xor(mx, m, 64));
        float sm = 0.f;
#pragma unroll
        for (int e = 0; e < 4; ++e) { v[e] = expf(v[e] - mx); sm += v[e]; }
#pragma unroll
        for (int m = 1; m < 8; m <<= 1) sm += __shfl_xor(sm, m, 64);
        const float inv = 1.0f / sm;
#pragma unroll
        for (int e = 0; e < 4; ++e) P[(q << 5) + (u << 2) + e] = (bf16)(v[e] * inv);
    }
    __syncthreads();

    bf16x8 pa[2];
#pragma unroll
    for (int i = 0; i < 2; ++i)
        pa[i] = *(const bf16x8*)&P[(((i << 4) + l15) << 5) + (l4 << 3)];

    for (int ci = 0; ci < 3; ++ci) {
        const int cc = (ci == 0) ? 2 : (ci - 1);
        if (ci) {
            __syncthreads();
            stage_chunk(cc);
            __syncthreads();
        }
        f32x4 pacc[2][6] = {};
#pragma unroll
        for (int jn = 0; jn < 6; ++jn) {
            const int nl = w * 96 + (jn << 4) + l15;
            const int gg = nl >> 3, e = nl & 7;
            bf16x8 bv;
#pragma unroll
            for (int j = 0; j < 8; ++j) {
                const int kr = (l4 << 3) + j;
                bv[j] = yw[(((kr * 48) + (gg ^ fswz(kr))) << 3) + e];
            }
#pragma unroll
            for (int i = 0; i < 2; ++i)
                pacc[i][jn] = __builtin_amdgcn_mfma_f32_16x16x32_bf16(pa[i], bv, pacc[i][jn], 0, 0, 0);
        }
        // stage results to LDS (2-way-free: stride 388 -> l4 groups alternate 16-bank halves)
#pragma unroll
        for (int i = 0; i < 2; ++i)
#pragma unroll
            for (int jn = 0; jn < 6; ++jn)
#pragma unroll
                for (int r = 0; r < 4; ++r)
                    ostg[((i << 4) + (l4 << 2) + r) * OSTG_STRIDE + w * 96 + (jn << 4) + l15] =
                        pacc[i][jn][r];
        __syncthreads();
        // coalesced write-out: per instruction a wave covers 8 rows x 128B full lines
        {
            const int row = t >> 3;
            const int cb = (t & 7) << 2;
            float* orow = op + (size_t)row * 1152 + cc * 384;
            const float* srow = &ostg[row * OSTG_STRIDE];
#pragma unroll
            for (int k2 = 0; k2 < 12; ++k2) {
                const int c = cb + (k2 << 5);
                *(float4*)(orow + c) = *(const float4*)(srow + c);
            }
        }
        if (ci < 2) continue;   // next iteration's leading sync orders ostg reuse
    }
}

// ---------------- launcher ----------------
extern "C" void kernel_launch(void* const* d_in, const int* in_sizes, int n_in,
                              void* d_out, int out_size, void* d_ws, size_t ws_size,
                              hipStream_t stream)
{
    const float* x   = (const float*)d_in[0];
    const float* W1  = (const float*)d_in[1];
    const float* b1  = (const float*)d_in[2];
    const float* g1  = (const float*)d_in[3];
    const float* be1 = (const float*)d_in[4];
    const float* W2  = (const float*)d_in[5];
    const float* b2  = (const float*)d_in[6];
    const float* g2  = (const float*)d_in[7];
    const float* be2 = (const float*)d_in[8];
    const float* W3  = (const float*)d_in[9];
    const float* b3  = (const float*)d_in[10];
    const float* g3  = (const float*)d_in[11];
    const float* be3 = (const float*)d_in[12];
    const float* Wo  = (const float*)d_in[13];
    const float* bo  = (const float*)d_in[14];
    const float* cw1 = (const float*)d_in[15];
    const float* cb1 = (const float*)d_in[16];
    const float* cw2 = (const float*)d_in[17];
    const float* cb2 = (const float*)d_in[18];
    float* out = (float*)d_out;

    const int M = 8 * 9216;  // 73728 rows
    size_t off = 0;
    auto alloc = [&](size_t nbytes) {
        void* p = (char*)d_ws + off;
        off += (nbytes + 255) & ~(size_t)255;
        return p;
    };
    bf16* Yb  = (bf16*)alloc((size_t)M * 1152 * 2);  // x-bf16 early, Y late
    bf16* Hb  = (bf16*)alloc((size_t)M * 768 * 2);   // H1; later reused as H3
    bf16* H2  = (bf16*)alloc((size_t)M * 512 * 2);
    bf16* Wt1 = (bf16*)alloc(768ull * 1152 * 2);
    bf16* Wt2 = (bf16*)alloc(512ull * 768 * 2);
    bf16* Wt3 = (bf16*)alloc(256ull * 512 * 2);
    bf16* Wto = (bf16*)alloc(1152ull * 256 * 2);
    float* ppart = (float*)alloc(8ull * 36 * 1152 * 4);
    float* sbuf  = (float*)alloc(8ull * 1152 * 4);
    bf16* Xb = Yb;
    bf16* H1 = Hb;
    bf16* H3 = Hb;

    cvt_f32_bf16_kernel<<<41472, 256, 0, stream>>>(x, Xb, (size_t)M * 1152);
    wtrans_all_kernel<<<416, 256, 0, stream>>>(W1, Wt1, W2, Wt2, W3, Wt3, Wo, Wto);

    gemm_bf16_kernel<<<6 * 576, 256, 0, stream>>>(Xb, Wt1, b1, H1, 1152, 768, 6, 1);
    ln768_kernel<<<M / 2, 256, 0, stream>>>(H1, g1, be1);
    gemm_bf16_kernel<<<4 * 576, 256, 0, stream>>>(H1, Wt2, b2, H2, 768, 512, 4, 1);
    ln512_kernel<<<M / 4, 256, 0, stream>>>(H2, g2, be2);
    gemm_bf16_kernel<<<2 * 576, 256, 0, stream>>>(H2, Wt3, b3, H3, 512, 256, 2, 1);
    ln256_kernel<<<M / 8, 256, 0, stream>>>(H3, g3, be3);
    gemm_bf16_kernel<<<9 * 576, 256, 0, stream>>>(H3, Wto, bo, Yb, 256, 1152, 9, 0);

    pool1_kernel<<<dim3(9, 36, 8), 128, 0, stream>>>(Yb, ppart);
    se_kernel<<<8, 256, 0, stream>>>(ppart, cw1, cb1, cw2, cb2, sbuf);
    attn_kernel<<<dim3(288, 8), 256, 0, stream>>>(Yb, sbuf, out);
}

// Round 10
// 821.992 us; speedup vs baseline: 1.2007x; 1.0755x over previous
//
#include <hip/hip_runtime.h>
#include <cstdint>
#include <cstddef>

typedef __bf16 bf16;
typedef __bf16 bf16x8 __attribute__((ext_vector_type(8)));
typedef float f32x4 __attribute__((ext_vector_type(4)));

__device__ __forceinline__ void gload_lds16(const bf16* g, bf16* l) {
    __builtin_amdgcn_global_load_lds((const __attribute__((address_space(1))) void*)g,
                                     (__attribute__((address_space(3))) void*)l, 16, 0, 0);
}

// ---------------- f32 -> bf16 conversion ----------------
__global__ void cvt_f32_bf16_kernel(const float* __restrict__ in, bf16* __restrict__ outp, size_t n) {
    const size_t i = ((size_t)blockIdx.x * 256 + threadIdx.x) * 8;
    if (i >= n) return;
    const float4 a = *(const float4*)(in + i);
    const float4 b = *(const float4*)(in + i + 4);
    bf16x8 o;
    o[0] = (bf16)a.x; o[1] = (bf16)a.y; o[2] = (bf16)a.z; o[3] = (bf16)a.w;
    o[4] = (bf16)b.x; o[5] = (bf16)b.y; o[6] = (bf16)b.z; o[7] = (bf16)b.w;
    *(bf16x8*)(outp + i) = o;
}

// ---------------- all 4 weight transposes in one launch ----------------
__global__ void wtrans_all_kernel(const float* __restrict__ W1, bf16* __restrict__ T1,
                                  const float* __restrict__ W2, bf16* __restrict__ T2,
                                  const float* __restrict__ W3, bf16* __restrict__ T3,
                                  const float* __restrict__ Wo, bf16* __restrict__ To)
{
    __shared__ bf16 tile[64][65];
    const int id = blockIdx.x;
    const int t = threadIdx.x;
    const float* W; bf16* T; int K, N, kb, nb;
    if (id < 216)      { W = W1; T = T1; K = 1152; N = 768;  const int r = id;       kb = r % 18; nb = r / 18; }
    else if (id < 312) { W = W2; T = T2; K = 768;  N = 512;  const int r = id - 216; kb = r % 12; nb = r / 12; }
    else if (id < 344) { W = W3; T = T3; K = 512;  N = 256;  const int r = id - 312; kb = r % 8;  nb = r / 8;  }
    else               { W = Wo; T = To; K = 256;  N = 1152; const int r = id - 344; kb = r % 4;  nb = r / 4;  }
    const int k0 = kb << 6;
    const int n0 = nb << 6;
#pragma unroll
    for (int i = 0; i < 16; ++i) {
        const int flat = i * 256 + t;
        const int r = flat >> 6;
        const int c = flat & 63;
        tile[c][r] = (bf16)W[(size_t)(k0 + r) * N + n0 + c];
    }
    __syncthreads();
#pragma unroll
    for (int i = 0; i < 16; ++i) {
        const int flat = i * 256 + t;
        const int r = flat >> 6;
        const int c = flat & 63;
        T[(size_t)(n0 + r) * K + k0 + c] = tile[r][c];
    }
}

// XCD-aware bijective swizzle (requires nwg % 8 == 0)
__device__ __forceinline__ int xcd_swz(int bid, int nwg) {
    return (bid & 7) * (nwg >> 3) + (bid >> 3);
}

// ---------------- GEMM (bf16 A): C = A @ Bt^T + bias, optional GELU, optional column-pool ----------------
__global__ void gemm_bf16_kernel(const bf16* __restrict__ A, const bf16* __restrict__ Bt,
                                 const float* __restrict__ bias, bf16* __restrict__ C,
                                 int K, int N, int nx, int do_gelu,
                                 float* __restrict__ ppart)
{
    __shared__ bf16 Alds[128 * 64];
    __shared__ bf16 Blds[128 * 64];
    __shared__ float psum[2][128];
    const int t = threadIdx.x;
    const int w = t >> 6;
    const int l = t & 63;
    const int l15 = l & 15, l4 = l >> 4;
    const int wgid = xcd_swz(blockIdx.x, gridDim.x);
    const int mblk = wgid / nx;
    const int nblk = wgid - mblk * nx;
    const int m0 = mblk << 7;
    const int n0 = nblk << 7;
    const int wm = (w >> 1) << 6;
    const int wn = (w & 1) << 6;

    f32x4 acc[4][4] = {};

    int sr[4], sg[4];
#pragma unroll
    for (int i = 0; i < 4; ++i) {
        const int flat = i * 256 + t;
        sr[i] = flat >> 3;
        sg[i] = ((flat & 7) ^ (sr[i] & 7)) << 3;
    }

    for (int k0 = 0; k0 < K; k0 += 64) {
#pragma unroll
        for (int i = 0; i < 4; ++i) {
            gload_lds16(A + (size_t)(m0 + sr[i]) * K + (k0 + sg[i]),
                        &Alds[(size_t)(i * 256 + (w << 6)) << 3]);
            gload_lds16(Bt + (size_t)(n0 + sr[i]) * K + (k0 + sg[i]),
                        &Blds[(size_t)(i * 256 + (w << 6)) << 3]);
        }
        __syncthreads();
#pragma unroll
        for (int kk = 0; kk < 2; ++kk) {
            bf16x8 af[4], bfv[4];
#pragma unroll
            for (int i = 0; i < 4; ++i) {
                const int r = wm + (i << 4) + l15;
                const int g = (kk << 2) + l4;
                af[i] = *(const bf16x8*)&Alds[(r << 6) + ((g ^ (r & 7)) << 3)];
                const int rn = wn + (i << 4) + l15;
                bfv[i] = *(const bf16x8*)&Blds[(rn << 6) + ((g ^ (rn & 7)) << 3)];
            }
#pragma unroll
            for (int i = 0; i < 4; ++i)
#pragma unroll
                for (int j = 0; j < 4; ++j)
                    acc[i][j] = __builtin_amdgcn_mfma_f32_16x16x32_bf16(af[i], bfv[j], acc[i][j], 0, 0, 0);
        }
        __syncthreads();
    }

#pragma unroll
    for (int i = 0; i < 4; ++i) {
        const int mb = m0 + wm + (i << 4) + (l4 << 2);
#pragma unroll
        for (int j = 0; j < 4; ++j) {
            const int col = n0 + wn + (j << 4) + l15;
            const float bv = bias[col];
#pragma unroll
            for (int r = 0; r < 4; ++r) {
                float v = acc[i][j][r] + bv;
                if (do_gelu) v = 0.5f * v * (1.0f + erff(v * 0.70710678118654752f));
                C[(size_t)(mb + r) * N + col] = (bf16)v;
            }
        }
    }

    // fused column-pool partials: ppart[mblk][col] = sum of this block's 128 rows (with bias)
    if (ppart) {
#pragma unroll
        for (int j = 0; j < 4; ++j) {
            float cs = 0.f;
#pragma unroll
            for (int i = 0; i < 4; ++i)
#pragma unroll
                for (int r = 0; r < 4; ++r) cs += acc[i][j][r];
            cs += __shfl_xor(cs, 16, 64);
            cs += __shfl_xor(cs, 32, 64);   // summed over l4 -> 64 rows of this wave
            if (l4 == 0) psum[w >> 1][((w & 1) << 6) + (j << 4) + l15] = cs;
        }
        __syncthreads();
        if (t < 128) {
            const int col = n0 + t;
            // bias contributes 128 * bias[col] to this block's partial row-sum
            ppart[(size_t)mblk * N + col] = psum[0][t] + psum[1][t] + 128.0f * bias[col];
        }
    }
}

// ---------------- LayerNorms ----------------
__global__ void ln768_kernel(bf16* __restrict__ H, const float* __restrict__ g,
                             const float* __restrict__ be)
{
    const int t = threadIdx.x;
    const int rloc = t >> 7;
    const int u = t & 127;
    bf16* hp = H + ((size_t)blockIdx.x * 2 + rloc) * 768;
    float v[8];
    float s1 = 0.f, s2 = 0.f;
    if (u < 96) {
        const bf16x8 hv = *(const bf16x8*)(hp + u * 8);
#pragma unroll
        for (int e = 0; e < 8; ++e) { v[e] = (float)hv[e]; s1 += v[e]; s2 += v[e] * v[e]; }
    }
#pragma unroll
    for (int m = 1; m < 64; m <<= 1) { s1 += __shfl_xor(s1, m, 64); s2 += __shfl_xor(s2, m, 64); }
    __shared__ float red[8];
    const int w = t >> 6;
    if ((t & 63) == 0) { red[w] = s1; red[w + 4] = s2; }
    __syncthreads();
    const int wb = rloc << 1;
    s1 = red[wb] + red[wb + 1];
    s2 = red[wb + 4] + red[wb + 5];
    const float mu = s1 * (1.0f / 768.0f);
    const float rstd = rsqrtf(s2 * (1.0f / 768.0f) - mu * mu + 1e-5f);
    if (u < 96) {
        const float4 g0 = *(const float4*)(g + u * 8);
        const float4 g1 = *(const float4*)(g + u * 8 + 4);
        const float4 b0 = *(const float4*)(be + u * 8);
        const float4 b1 = *(const float4*)(be + u * 8 + 4);
        bf16x8 o;
        o[0] = (bf16)((v[0] - mu) * rstd * g0.x + b0.x);
        o[1] = (bf16)((v[1] - mu) * rstd * g0.y + b0.y);
        o[2] = (bf16)((v[2] - mu) * rstd * g0.z + b0.z);
        o[3] = (bf16)((v[3] - mu) * rstd * g0.w + b0.w);
        o[4] = (bf16)((v[4] - mu) * rstd * g1.x + b1.x);
        o[5] = (bf16)((v[5] - mu) * rstd * g1.y + b1.y);
        o[6] = (bf16)((v[6] - mu) * rstd * g1.z + b1.z);
        o[7] = (bf16)((v[7] - mu) * rstd * g1.w + b1.w);
        *(bf16x8*)(hp + u * 8) = o;
    }
}

__global__ void ln512_kernel(bf16* __restrict__ H, const float* __restrict__ g,
                             const float* __restrict__ be)
{
    const int t = threadIdx.x;
    const int w = t >> 6, l = t & 63;
    bf16* hp = H + ((size_t)blockIdx.x * 4 + w) * 512;
    const bf16x8 hv = *(const bf16x8*)(hp + l * 8);
    float v[8];
    float s1 = 0.f, s2 = 0.f;
#pragma unroll
    for (int e = 0; e < 8; ++e) { v[e] = (float)hv[e]; s1 += v[e]; s2 += v[e] * v[e]; }
#pragma unroll
    for (int m = 1; m < 64; m <<= 1) { s1 += __shfl_xor(s1, m, 64); s2 += __shfl_xor(s2, m, 64); }
    const float mu = s1 * (1.0f / 512.0f);
    const float rstd = rsqrtf(s2 * (1.0f / 512.0f) - mu * mu + 1e-5f);
    const float4 g0 = *(const float4*)(g + l * 8);
    const float4 g1 = *(const float4*)(g + l * 8 + 4);
    const float4 b0 = *(const float4*)(be + l * 8);
    const float4 b1 = *(const float4*)(be + l * 8 + 4);
    bf16x8 o;
    o[0] = (bf16)((v[0] - mu) * rstd * g0.x + b0.x);
    o[1] = (bf16)((v[1] - mu) * rstd * g0.y + b0.y);
    o[2] = (bf16)((v[2] - mu) * rstd * g0.z + b0.z);
    o[3] = (bf16)((v[3] - mu) * rstd * g0.w + b0.w);
    o[4] = (bf16)((v[4] - mu) * rstd * g1.x + b1.x);
    o[5] = (bf16)((v[5] - mu) * rstd * g1.y + b1.y);
    o[6] = (bf16)((v[6] - mu) * rstd * g1.z + b1.z);
    o[7] = (bf16)((v[7] - mu) * rstd * g1.w + b1.w);
    *(bf16x8*)(hp + l * 8) = o;
}

__global__ void ln256_kernel(bf16* __restrict__ H, const float* __restrict__ g,
                             const float* __restrict__ be)
{
    const int t = threadIdx.x;
    const int rloc = t >> 5, l = t & 31;
    bf16* hp = H + ((size_t)blockIdx.x * 8 + rloc) * 256;
    const bf16x8 hv = *(const bf16x8*)(hp + l * 8);
    float v[8];
    float s1 = 0.f, s2 = 0.f;
#pragma unroll
    for (int e = 0; e < 8; ++e) { v[e] = (float)hv[e]; s1 += v[e]; s2 += v[e] * v[e]; }
#pragma unroll
    for (int m = 1; m < 32; m <<= 1) { s1 += __shfl_xor(s1, m, 64); s2 += __shfl_xor(s2, m, 64); }
    const float mu = s1 * (1.0f / 256.0f);
    const float rstd = rsqrtf(s2 * (1.0f / 256.0f) - mu * mu + 1e-5f);
    const float4 g0 = *(const float4*)(g + l * 8);
    const float4 g1 = *(const float4*)(g + l * 8 + 4);
    const float4 b0 = *(const float4*)(be + l * 8);
    const float4 b1 = *(const float4*)(be + l * 8 + 4);
    bf16x8 o;
    o[0] = (bf16)((v[0] - mu) * rstd * g0.x + b0.x);
    o[1] = (bf16)((v[1] - mu) * rstd * g0.y + b0.y);
    o[2] = (bf16)((v[2] - mu) * rstd * g0.z + b0.z);
    o[3] = (bf16)((v[3] - mu) * rstd * g0.w + b0.w);
    o[4] = (bf16)((v[4] - mu) * rstd * g1.x + b1.x);
    o[5] = (bf16)((v[5] - mu) * rstd * g1.y + b1.y);
    o[6] = (bf16)((v[6] - mu) * rstd * g1.z + b1.z);
    o[7] = (bf16)((v[7] - mu) * rstd * g1.w + b1.w);
    *(bf16x8*)(hp + l * 8) = o;
}

// ---------------- SE MLP (pool finish: sum 72 m-block partials per batch) ----------------
__global__ void se_kernel(const float* __restrict__ ppart,
                          const float* __restrict__ w1, const float* __restrict__ b1,
                          const float* __restrict__ w2, const float* __restrict__ b2,
                          float* __restrict__ sbuf)
{
    const int b = blockIdx.x, t = threadIdx.x;
    __shared__ float p[1152];
    __shared__ float t1[144];
    for (int c = t; c < 1152; c += 256) {
        float s = 0.f;
#pragma unroll 8
        for (int j = 0; j < 72; ++j) s += ppart[(size_t)(b * 72 + j) * 1152 + c];
        p[c] = s * (1.0f / 9216.0f);
    }
    __syncthreads();
    if (t < 144) {
        float a = b1[t];
        for (int k = 0; k < 1152; ++k) a += p[k] * w1[k * 144 + t];
        t1[t] = a > 0.f ? a : 0.f;
    }
    __syncthreads();
    for (int c = t; c < 1152; c += 256) {
        float a = b2[c];
#pragma unroll 8
        for (int k = 0; k < 144; ++k) a += t1[k] * w2[k * 1152 + c];
        sbuf[b * 1152 + c] = 1.0f / (1.0f + expf(-a));
    }
}

// ---------------- windowed self-attention ----------------
// yw row-major XOR-swizzled; output staged 16 rows at a time in LDS (51.4KB total -> 3 blocks/CU)
__device__ __forceinline__ int fswz(int r) { return (r & 7) ^ ((r >> 3) & 3); }

#define OSTG_STRIDE 388

__global__ void attn_kernel(const bf16* __restrict__ Y, const float* __restrict__ sbuf,
                            float* __restrict__ out)
{
    // 24576 (yw) + 24832 (ostg16 / Sp union) + 2048 (P) = 51456 B -> 3 blocks/CU
    __shared__ __align__(16) char smem[24576 + 24832 + 2048];
    bf16*  yw   = (bf16*)smem;                       // [32][384] swizzled
    float* SpF  = (float*)(smem + 24576);            // [4][32][33] (score phase only)
    float* ostg = (float*)(smem + 24576);            // [16][388]  (PV phase only)
    bf16*  P    = (bf16*)(smem + 24576 + 24832);     // [32][32]

    const int t = threadIdx.x;
    const int w = t >> 6, l = t & 63;
    const int l15 = l & 15, l4 = l >> 4;
    const int wdx = blockIdx.x, b = blockIdx.y;

    const bf16* Yp = Y + ((size_t)b * 9216 + (size_t)wdx * 32) * 1152;
    const float* sv = sbuf + b * 1152;
    float* op = out + ((size_t)b * 9216 + (size_t)wdx * 32) * 1152;

    auto stage_chunk = [&](int cc) {
#pragma unroll
        for (int i = 0; i < 6; ++i) {
            const int flat = i * 256 + t;
            const int r = flat / 48;
            const int gg = flat - r * 48;
            const int c0 = cc * 384 + gg * 8;
            const bf16x8 yv = *(const bf16x8*)(Yp + (size_t)r * 1152 + c0);
            const float4 sa = *(const float4*)(sv + c0);
            const float4 sb = *(const float4*)(sv + c0 + 4);
            bf16x8 ov;
            ov[0] = (bf16)((float)yv[0] * sa.x);
            ov[1] = (bf16)((float)yv[1] * sa.y);
            ov[2] = (bf16)((float)yv[2] * sa.z);
            ov[3] = (bf16)((float)yv[3] * sa.w);
            ov[4] = (bf16)((float)yv[4] * sb.x);
            ov[5] = (bf16)((float)yv[5] * sb.y);
            ov[6] = (bf16)((float)yv[6] * sb.z);
            ov[7] = (bf16)((float)yv[7] * sb.w);
            *(bf16x8*)&yw[((r * 48) + (gg ^ fswz(r))) << 3] = ov;
        }
    };

    f32x4 acc[2][2] = {};
    for (int cc = 0; cc < 3; ++cc) {
        if (cc) __syncthreads();
        stage_chunk(cc);
        __syncthreads();
#pragma unroll
        for (int kkl = 0; kkl < 3; ++kkl) {
            const int g = ((w * 3 + kkl) << 2) + l4;
            bf16x8 af[2];
#pragma unroll
            for (int i = 0; i < 2; ++i) {
                const int r = (i << 4) + l15;
                af[i] = *(const bf16x8*)&yw[((r * 48) + (g ^ fswz(r))) << 3];
            }
#pragma unroll
            for (int i = 0; i < 2; ++i)
#pragma unroll
                for (int j = 0; j < 2; ++j)
                    acc[i][j] = __builtin_amdgcn_mfma_f32_16x16x32_bf16(af[i], af[j], acc[i][j], 0, 0, 0);
        }
    }
#pragma unroll
    for (int i = 0; i < 2; ++i)
#pragma unroll
        for (int j = 0; j < 2; ++j)
#pragma unroll
            for (int r = 0; r < 4; ++r)
                SpF[w * 1056 + ((i << 4) + (l4 << 2) + r) * 33 + (j << 4) + l15] = acc[i][j][r];
    __syncthreads();

    {
        const int q = t >> 3, u = t & 7;
        float v[4];
#pragma unroll
        for (int e = 0; e < 4; ++e) {
            const int k2 = (u << 2) + e;
            v[e] = (SpF[q * 33 + k2] + SpF[1056 + q * 33 + k2] +
                    SpF[2112 + q * 33 + k2] + SpF[3168 + q * 33 + k2]) * 0.029462782549439483f;
        }
        float mx = fmaxf(fmaxf(v[0], v[1]), fmaxf(v[2], v[3]));
#pragma unroll
        for (int m = 1; m < 8; m <<= 1) mx = fmaxf(mx, __shfl_xor(mx, m, 64));
        float sm = 0.f;
#pragma unroll
        for (int e = 0; e < 4; ++e) { v[e] = expf(v[e] - mx); sm += v[e]; }
#pragma unroll
        for (int m = 1; m < 8; m <<= 1) sm += __shfl_xor(sm, m, 64);
        const float inv = 1.0f / sm;
#pragma unroll
        for (int e = 0; e < 4; ++e) P[(q << 5) + (u << 2) + e] = (bf16)(v[e] * inv);
    }
    __syncthreads();

    bf16x8 pa[2];
#pragma unroll
    for (int i = 0; i < 2; ++i)
        pa[i] = *(const bf16x8*)&P[(((i << 4) + l15) << 5) + (l4 << 3)];

    for (int ci = 0; ci < 3; ++ci) {
        const int cc = (ci == 0) ? 2 : (ci - 1);
        if (ci) {
            __syncthreads();
            stage_chunk(cc);
            __syncthreads();
        }
        f32x4 pacc[2][6] = {};
#pragma unroll
        for (int jn = 0; jn < 6; ++jn) {
            const int nl = w * 96 + (jn << 4) + l15;
            const int gg = nl >> 3, e = nl & 7;
            bf16x8 bv;
#pragma unroll
            for (int j = 0; j < 8; ++j) {
                const int kr = (l4 << 3) + j;
                bv[j] = yw[(((kr * 48) + (gg ^ fswz(kr))) << 3) + e];
            }
#pragma unroll
            for (int i = 0; i < 2; ++i)
                pacc[i][jn] = __builtin_amdgcn_mfma_f32_16x16x32_bf16(pa[i], bv, pacc[i][jn], 0, 0, 0);
        }
        // two 16-row staging passes through ostg (write 2-way-free, read+writeout full lines)
#pragma unroll
        for (int half = 0; half < 2; ++half) {
            if (half) __syncthreads();   // order vs previous read pass
#pragma unroll
            for (int jn = 0; jn < 6; ++jn)
#pragma unroll
                for (int r = 0; r < 4; ++r)
                    ostg[((l4 << 2) + r) * OSTG_STRIDE + w * 96 + (jn << 4) + l15] =
                        pacc[half][jn][r];
            __syncthreads();
            {
                const int row = t >> 4;                 // 0..15
                const int cb = (t & 15) << 2;
                float* orow = op + (size_t)(row + (half << 4)) * 1152 + cc * 384;
                const float* srow = &ostg[row * OSTG_STRIDE];
#pragma unroll
                for (int k2 = 0; k2 < 6; ++k2) {
                    const int c = cb + (k2 << 6);
                    *(float4*)(orow + c) = *(const float4*)(srow + c);
                }
            }
        }
        if (ci < 2) __syncthreads();     // ostg/yw reuse ordering before next stage
    }
}

// ---------------- launcher ----------------
extern "C" void kernel_launch(void* const* d_in, const int* in_sizes, int n_in,
                              void* d_out, int out_size, void* d_ws, size_t ws_size,
                              hipStream_t stream)
{
    const float* x   = (const float*)d_in[0];
    const float* W1  = (const float*)d_in[1];
    const float* b1  = (const float*)d_in[2];
    const float* g1  = (const float*)d_in[3];
    const float* be1 = (const float*)d_in[4];
    const float* W2  = (const float*)d_in[5];
    const float* b2  = (const float*)d_in[6];
    const float* g2  = (const float*)d_in[7];
    const float* be2 = (const float*)d_in[8];
    const float* W3  = (const float*)d_in[9];
    const float* b3  = (const float*)d_in[10];
    const float* g3  = (const float*)d_in[11];
    const float* be3 = (const float*)d_in[12];
    const float* Wo  = (const float*)d_in[13];
    const float* bo  = (const float*)d_in[14];
    const float* cw1 = (const float*)d_in[15];
    const float* cb1 = (const float*)d_in[16];
    const float* cw2 = (const float*)d_in[17];
    const float* cb2 = (const float*)d_in[18];
    float* out = (float*)d_out;

    const int M = 8 * 9216;  // 73728 rows
    size_t off = 0;
    auto alloc = [&](size_t nbytes) {
        void* p = (char*)d_ws + off;
        off += (nbytes + 255) & ~(size_t)255;
        return p;
    };
    bf16* Yb  = (bf16*)alloc((size_t)M * 1152 * 2);  // x-bf16 early, Y late
    bf16* Hb  = (bf16*)alloc((size_t)M * 768 * 2);   // H1; later reused as H3
    bf16* H2  = (bf16*)alloc((size_t)M * 512 * 2);
    bf16* Wt1 = (bf16*)alloc(768ull * 1152 * 2);
    bf16* Wt2 = (bf16*)alloc(512ull * 768 * 2);
    bf16* Wt3 = (bf16*)alloc(256ull * 512 * 2);
    bf16* Wto = (bf16*)alloc(1152ull * 256 * 2);
    float* ppart = (float*)alloc(576ull * 1152 * 4); // per-mblk column partials
    float* sbuf  = (float*)alloc(8ull * 1152 * 4);
    bf16* Xb = Yb;
    bf16* H1 = Hb;
    bf16* H3 = Hb;

    cvt_f32_bf16_kernel<<<41472, 256, 0, stream>>>(x, Xb, (size_t)M * 1152);
    wtrans_all_kernel<<<416, 256, 0, stream>>>(W1, Wt1, W2, Wt2, W3, Wt3, Wo, Wto);

    gemm_bf16_kernel<<<6 * 576, 256, 0, stream>>>(Xb, Wt1, b1, H1, 1152, 768, 6, 1, nullptr);
    ln768_kernel<<<M / 2, 256, 0, stream>>>(H1, g1, be1);
    gemm_bf16_kernel<<<4 * 576, 256, 0, stream>>>(H1, Wt2, b2, H2, 768, 512, 4, 1, nullptr);
    ln512_kernel<<<M / 4, 256, 0, stream>>>(H2, g2, be2);
    gemm_bf16_kernel<<<2 * 576, 256, 0, stream>>>(H2, Wt3, b3, H3, 512, 256, 2, 1, nullptr);
    ln256_kernel<<<M / 8, 256, 0, stream>>>(H3, g3, be3);
    gemm_bf16_kernel<<<9 * 576, 256, 0, stream>>>(H3, Wto, bo, Yb, 256, 1152, 9, 0, ppart);

    se_kernel<<<8, 256, 0, stream>>>(ppart, cw1, cb1, cw2, cb2, sbuf);
    attn_kernel<<<dim3(288, 8), 256, 0, stream>>>(Yb, sbuf, out);
}

// Round 11
// 804.738 us; speedup vs baseline: 1.2265x; 1.0214x over previous
//
#include <hip/hip_runtime.h>
#include <cstdint>
#include <cstddef>

typedef __bf16 bf16;
typedef __bf16 bf16x8 __attribute__((ext_vector_type(8)));
typedef float f32x4 __attribute__((ext_vector_type(4)));

__device__ __forceinline__ void gload_lds16(const bf16* g, bf16* l) {
    __builtin_amdgcn_global_load_lds((const __attribute__((address_space(1))) void*)g,
                                     (__attribute__((address_space(3))) void*)l, 16, 0, 0);
}
__device__ __forceinline__ void gload_lds16f(const float* g, float* l) {
    __builtin_amdgcn_global_load_lds((const __attribute__((address_space(1))) void*)g,
                                     (__attribute__((address_space(3))) void*)l, 16, 0, 0);
}

// ---------------- all 4 weight transposes in one launch ----------------
__global__ void wtrans_all_kernel(const float* __restrict__ W1, bf16* __restrict__ T1,
                                  const float* __restrict__ W2, bf16* __restrict__ T2,
                                  const float* __restrict__ W3, bf16* __restrict__ T3,
                                  const float* __restrict__ Wo, bf16* __restrict__ To)
{
    __shared__ bf16 tile[64][65];
    const int id = blockIdx.x;
    const int t = threadIdx.x;
    const float* W; bf16* T; int K, N, kb, nb;
    if (id < 216)      { W = W1; T = T1; K = 1152; N = 768;  const int r = id;       kb = r % 18; nb = r / 18; }
    else if (id < 312) { W = W2; T = T2; K = 768;  N = 512;  const int r = id - 216; kb = r % 12; nb = r / 12; }
    else if (id < 344) { W = W3; T = T3; K = 512;  N = 256;  const int r = id - 312; kb = r % 8;  nb = r / 8;  }
    else               { W = Wo; T = To; K = 256;  N = 1152; const int r = id - 344; kb = r % 4;  nb = r / 4;  }
    const int k0 = kb << 6;
    const int n0 = nb << 6;
#pragma unroll
    for (int i = 0; i < 16; ++i) {
        const int flat = i * 256 + t;
        const int r = flat >> 6;
        const int c = flat & 63;
        tile[c][r] = (bf16)W[(size_t)(k0 + r) * N + n0 + c];
    }
    __syncthreads();
#pragma unroll
    for (int i = 0; i < 16; ++i) {
        const int flat = i * 256 + t;
        const int r = flat >> 6;
        const int c = flat & 63;
        T[(size_t)(n0 + r) * K + k0 + c] = tile[r][c];
    }
}

// XCD-aware bijective swizzle (requires nwg % 8 == 0)
__device__ __forceinline__ int xcd_swz(int bid, int nwg) {
    return (bid & 7) * (nwg >> 3) + (bid >> 3);
}

// ---------------- GEMM1 (f32 A direct, fused cvt + GELU) ----------------
// A staged as f32 via global_load_lds with 4-bit XOR slot swizzle (slot = grp ^ (row&15)):
// frag-read bank-start (2*l4 ^ l15&7)*4 covers all 32 banks at 2 lanes/bank -> conflict-free.
__global__ void gemm_f32a_kernel(const float* __restrict__ A, const bf16* __restrict__ Bt,
                                 const float* __restrict__ bias, bf16* __restrict__ C,
                                 int K, int N, int nx)
{
    __shared__ float Af32[128 * 64];   // 32 KB
    __shared__ bf16  Blds[128 * 64];   // 16 KB
    const int t = threadIdx.x;
    const int w = t >> 6;
    const int l = t & 63;
    const int l15 = l & 15, l4 = l >> 4;
    const int wgid = xcd_swz(blockIdx.x, gridDim.x);
    const int mblk = wgid / nx;
    const int nblk = wgid - mblk * nx;
    const int m0 = mblk << 7;
    const int n0 = nblk << 7;
    const int wm = (w >> 1) << 6;
    const int wn = (w & 1) << 6;

    f32x4 acc[4][4] = {};

    // A staging map: 8 rounds, 16B (4 floats) per lane; slot = (flat&15), src grp = slot ^ (row&15)
    int ar[8], ag[8];
#pragma unroll
    for (int i = 0; i < 8; ++i) {
        const int flat = i * 256 + t;
        ar[i] = flat >> 4;
        ag[i] = ((flat & 15) ^ (ar[i] & 15)) << 2;   // float offset in row
    }
    int br[4], bg[4];
#pragma unroll
    for (int i = 0; i < 4; ++i) {
        const int flat = i * 256 + t;
        br[i] = flat >> 3;
        bg[i] = ((flat & 7) ^ (br[i] & 7)) << 3;
    }

    for (int k0 = 0; k0 < K; k0 += 64) {
#pragma unroll
        for (int i = 0; i < 8; ++i)
            gload_lds16f(A + (size_t)(m0 + ar[i]) * K + (k0 + ag[i]),
                         &Af32[(i * 256 + (w << 6)) << 2]);
#pragma unroll
        for (int i = 0; i < 4; ++i)
            gload_lds16(Bt + (size_t)(n0 + br[i]) * K + (k0 + bg[i]),
                        &Blds[(i * 256 + (w << 6)) << 3]);
        __syncthreads();
#pragma unroll
        for (int kk = 0; kk < 2; ++kk) {
            bf16x8 af[4], bfv[4];
#pragma unroll
            for (int i = 0; i < 4; ++i) {
                const int r = wm + (i << 4) + l15;
                const int s2 = (((kk << 2) + l4) << 1);
                const float4 fa = *(const float4*)&Af32[(r << 6) + ((s2 ^ (r & 15)) << 2)];
                const float4 fb = *(const float4*)&Af32[(r << 6) + (((s2 + 1) ^ (r & 15)) << 2)];
                bf16x8 a;
                a[0] = (bf16)fa.x; a[1] = (bf16)fa.y; a[2] = (bf16)fa.z; a[3] = (bf16)fa.w;
                a[4] = (bf16)fb.x; a[5] = (bf16)fb.y; a[6] = (bf16)fb.z; a[7] = (bf16)fb.w;
                af[i] = a;
                const int rn = wn + (i << 4) + l15;
                const int g = (kk << 2) + l4;
                bfv[i] = *(const bf16x8*)&Blds[(rn << 6) + ((g ^ (rn & 7)) << 3)];
            }
#pragma unroll
            for (int i = 0; i < 4; ++i)
#pragma unroll
                for (int j = 0; j < 4; ++j)
                    acc[i][j] = __builtin_amdgcn_mfma_f32_16x16x32_bf16(af[i], bfv[j], acc[i][j], 0, 0, 0);
        }
        __syncthreads();
    }

#pragma unroll
    for (int i = 0; i < 4; ++i) {
        const int mb = m0 + wm + (i << 4) + (l4 << 2);
#pragma unroll
        for (int j = 0; j < 4; ++j) {
            const int col = n0 + wn + (j << 4) + l15;
            const float bv = bias[col];
#pragma unroll
            for (int r = 0; r < 4; ++r) {
                float v = acc[i][j][r] + bv;
                v = 0.5f * v * (1.0f + erff(v * 0.70710678118654752f));
                C[(size_t)(mb + r) * N + col] = (bf16)v;
            }
        }
    }
}

// ---------------- GEMM (bf16 A, no pool): LDS exactly 48KB->32KB ----------------
__global__ void gemm_bf16_kernel(const bf16* __restrict__ A, const bf16* __restrict__ Bt,
                                 const float* __restrict__ bias, bf16* __restrict__ C,
                                 int K, int N, int nx, int do_gelu)
{
    __shared__ bf16 Alds[128 * 64];
    __shared__ bf16 Blds[128 * 64];
    const int t = threadIdx.x;
    const int w = t >> 6;
    const int l = t & 63;
    const int l15 = l & 15, l4 = l >> 4;
    const int wgid = xcd_swz(blockIdx.x, gridDim.x);
    const int mblk = wgid / nx;
    const int nblk = wgid - mblk * nx;
    const int m0 = mblk << 7;
    const int n0 = nblk << 7;
    const int wm = (w >> 1) << 6;
    const int wn = (w & 1) << 6;

    f32x4 acc[4][4] = {};

    int sr[4], sg[4];
#pragma unroll
    for (int i = 0; i < 4; ++i) {
        const int flat = i * 256 + t;
        sr[i] = flat >> 3;
        sg[i] = ((flat & 7) ^ (sr[i] & 7)) << 3;
    }

    for (int k0 = 0; k0 < K; k0 += 64) {
#pragma unroll
        for (int i = 0; i < 4; ++i) {
            gload_lds16(A + (size_t)(m0 + sr[i]) * K + (k0 + sg[i]),
                        &Alds[(size_t)(i * 256 + (w << 6)) << 3]);
            gload_lds16(Bt + (size_t)(n0 + sr[i]) * K + (k0 + sg[i]),
                        &Blds[(size_t)(i * 256 + (w << 6)) << 3]);
        }
        __syncthreads();
#pragma unroll
        for (int kk = 0; kk < 2; ++kk) {
            bf16x8 af[4], bfv[4];
#pragma unroll
            for (int i = 0; i < 4; ++i) {
                const int r = wm + (i << 4) + l15;
                const int g = (kk << 2) + l4;
                af[i] = *(const bf16x8*)&Alds[(r << 6) + ((g ^ (r & 7)) << 3)];
                const int rn = wn + (i << 4) + l15;
                bfv[i] = *(const bf16x8*)&Blds[(rn << 6) + ((g ^ (rn & 7)) << 3)];
            }
#pragma unroll
            for (int i = 0; i < 4; ++i)
#pragma unroll
                for (int j = 0; j < 4; ++j)
                    acc[i][j] = __builtin_amdgcn_mfma_f32_16x16x32_bf16(af[i], bfv[j], acc[i][j], 0, 0, 0);
        }
        __syncthreads();
    }

#pragma unroll
    for (int i = 0; i < 4; ++i) {
        const int mb = m0 + wm + (i << 4) + (l4 << 2);
#pragma unroll
        for (int j = 0; j < 4; ++j) {
            const int col = n0 + wn + (j << 4) + l15;
            const float bv = bias[col];
#pragma unroll
            for (int r = 0; r < 4; ++r) {
                float v = acc[i][j][r] + bv;
                if (do_gelu) v = 0.5f * v * (1.0f + erff(v * 0.70710678118654752f));
                C[(size_t)(mb + r) * N + col] = (bf16)v;
            }
        }
    }
}

// ---------------- GEMM with fused column-pool (output layer) ----------------
__global__ void gemm_pool_kernel(const bf16* __restrict__ A, const bf16* __restrict__ Bt,
                                 const float* __restrict__ bias, bf16* __restrict__ C,
                                 int K, int N, int nx, float* __restrict__ ppart)
{
    __shared__ bf16 Alds[128 * 64];
    __shared__ bf16 Blds[128 * 64];
    __shared__ float psum[2][128];
    const int t = threadIdx.x;
    const int w = t >> 6;
    const int l = t & 63;
    const int l15 = l & 15, l4 = l >> 4;
    const int wgid = xcd_swz(blockIdx.x, gridDim.x);
    const int mblk = wgid / nx;
    const int nblk = wgid - mblk * nx;
    const int m0 = mblk << 7;
    const int n0 = nblk << 7;
    const int wm = (w >> 1) << 6;
    const int wn = (w & 1) << 6;

    f32x4 acc[4][4] = {};

    int sr[4], sg[4];
#pragma unroll
    for (int i = 0; i < 4; ++i) {
        const int flat = i * 256 + t;
        sr[i] = flat >> 3;
        sg[i] = ((flat & 7) ^ (sr[i] & 7)) << 3;
    }

    for (int k0 = 0; k0 < K; k0 += 64) {
#pragma unroll
        for (int i = 0; i < 4; ++i) {
            gload_lds16(A + (size_t)(m0 + sr[i]) * K + (k0 + sg[i]),
                        &Alds[(size_t)(i * 256 + (w << 6)) << 3]);
            gload_lds16(Bt + (size_t)(n0 + sr[i]) * K + (k0 + sg[i]),
                        &Blds[(size_t)(i * 256 + (w << 6)) << 3]);
        }
        __syncthreads();
#pragma unroll
        for (int kk = 0; kk < 2; ++kk) {
            bf16x8 af[4], bfv[4];
#pragma unroll
            for (int i = 0; i < 4; ++i) {
                const int r = wm + (i << 4) + l15;
                const int g = (kk << 2) + l4;
                af[i] = *(const bf16x8*)&Alds[(r << 6) + ((g ^ (r & 7)) << 3)];
                const int rn = wn + (i << 4) + l15;
                bfv[i] = *(const bf16x8*)&Blds[(rn << 6) + ((g ^ (rn & 7)) << 3)];
            }
#pragma unroll
            for (int i = 0; i < 4; ++i)
#pragma unroll
                for (int j = 0; j < 4; ++j)
                    acc[i][j] = __builtin_amdgcn_mfma_f32_16x16x32_bf16(af[i], bfv[j], acc[i][j], 0, 0, 0);
        }
        __syncthreads();
    }

#pragma unroll
    for (int i = 0; i < 4; ++i) {
        const int mb = m0 + wm + (i << 4) + (l4 << 2);
#pragma unroll
        for (int j = 0; j < 4; ++j) {
            const int col = n0 + wn + (j << 4) + l15;
            const float bv = bias[col];
#pragma unroll
            for (int r = 0; r < 4; ++r)
                C[(size_t)(mb + r) * N + col] = (bf16)(acc[i][j][r] + bv);
        }
    }

#pragma unroll
    for (int j = 0; j < 4; ++j) {
        float cs = 0.f;
#pragma unroll
        for (int i = 0; i < 4; ++i)
#pragma unroll
            for (int r = 0; r < 4; ++r) cs += acc[i][j][r];
        cs += __shfl_xor(cs, 16, 64);
        cs += __shfl_xor(cs, 32, 64);
        if (l4 == 0) psum[w >> 1][((w & 1) << 6) + (j << 4) + l15] = cs;
    }
    __syncthreads();
    if (t < 128) {
        const int col = n0 + t;
        ppart[(size_t)mblk * N + col] = psum[0][t] + psum[1][t] + 128.0f * bias[col];
    }
}

// ---------------- LayerNorms ----------------
__global__ void ln768_kernel(bf16* __restrict__ H, const float* __restrict__ g,
                             const float* __restrict__ be)
{
    const int t = threadIdx.x;
    const int rloc = t >> 7;
    const int u = t & 127;
    bf16* hp = H + ((size_t)blockIdx.x * 2 + rloc) * 768;
    float v[8];
    float s1 = 0.f, s2 = 0.f;
    if (u < 96) {
        const bf16x8 hv = *(const bf16x8*)(hp + u * 8);
#pragma unroll
        for (int e = 0; e < 8; ++e) { v[e] = (float)hv[e]; s1 += v[e]; s2 += v[e] * v[e]; }
    }
#pragma unroll
    for (int m = 1; m < 64; m <<= 1) { s1 += __shfl_xor(s1, m, 64); s2 += __shfl_xor(s2, m, 64); }
    __shared__ float red[8];
    const int w = t >> 6;
    if ((t & 63) == 0) { red[w] = s1; red[w + 4] = s2; }
    __syncthreads();
    const int wb = rloc << 1;
    s1 = red[wb] + red[wb + 1];
    s2 = red[wb + 4] + red[wb + 5];
    const float mu = s1 * (1.0f / 768.0f);
    const float rstd = rsqrtf(s2 * (1.0f / 768.0f) - mu * mu + 1e-5f);
    if (u < 96) {
        const float4 g0 = *(const float4*)(g + u * 8);
        const float4 g1 = *(const float4*)(g + u * 8 + 4);
        const float4 b0 = *(const float4*)(be + u * 8);
        const float4 b1 = *(const float4*)(be + u * 8 + 4);
        bf16x8 o;
        o[0] = (bf16)((v[0] - mu) * rstd * g0.x + b0.x);
        o[1] = (bf16)((v[1] - mu) * rstd * g0.y + b0.y);
        o[2] = (bf16)((v[2] - mu) * rstd * g0.z + b0.z);
        o[3] = (bf16)((v[3] - mu) * rstd * g0.w + b0.w);
        o[4] = (bf16)((v[4] - mu) * rstd * g1.x + b1.x);
        o[5] = (bf16)((v[5] - mu) * rstd * g1.y + b1.y);
        o[6] = (bf16)((v[6] - mu) * rstd * g1.z + b1.z);
        o[7] = (bf16)((v[7] - mu) * rstd * g1.w + b1.w);
        *(bf16x8*)(hp + u * 8) = o;
    }
}

__global__ void ln512_kernel(bf16* __restrict__ H, const float* __restrict__ g,
                             const float* __restrict__ be)
{
    const int t = threadIdx.x;
    const int w = t >> 6, l = t & 63;
    bf16* hp = H + ((size_t)blockIdx.x * 4 + w) * 512;
    const bf16x8 hv = *(const bf16x8*)(hp + l * 8);
    float v[8];
    float s1 = 0.f, s2 = 0.f;
#pragma unroll
    for (int e = 0; e < 8; ++e) { v[e] = (float)hv[e]; s1 += v[e]; s2 += v[e] * v[e]; }
#pragma unroll
    for (int m = 1; m < 64; m <<= 1) { s1 += __shfl_xor(s1, m, 64); s2 += __shfl_xor(s2, m, 64); }
    const float mu = s1 * (1.0f / 512.0f);
    const float rstd = rsqrtf(s2 * (1.0f / 512.0f) - mu * mu + 1e-5f);
    const float4 g0 = *(const float4*)(g + l * 8);
    const float4 g1 = *(const float4*)(g + l * 8 + 4);
    const float4 b0 = *(const float4*)(be + l * 8);
    const float4 b1 = *(const float4*)(be + l * 8 + 4);
    bf16x8 o;
    o[0] = (bf16)((v[0] - mu) * rstd * g0.x + b0.x);
    o[1] = (bf16)((v[1] - mu) * rstd * g0.y + b0.y);
    o[2] = (bf16)((v[2] - mu) * rstd * g0.z + b0.z);
    o[3] = (bf16)((v[3] - mu) * rstd * g0.w + b0.w);
    o[4] = (bf16)((v[4] - mu) * rstd * g1.x + b1.x);
    o[5] = (bf16)((v[5] - mu) * rstd * g1.y + b1.y);
    o[6] = (bf16)((v[6] - mu) * rstd * g1.z + b1.z);
    o[7] = (bf16)((v[7] - mu) * rstd * g1.w + b1.w);
    *(bf16x8*)(hp + l * 8) = o;
}

__global__ void ln256_kernel(bf16* __restrict__ H, const float* __restrict__ g,
                             const float* __restrict__ be)
{
    const int t = threadIdx.x;
    const int rloc = t >> 5, l = t & 31;
    bf16* hp = H + ((size_t)blockIdx.x * 8 + rloc) * 256;
    const bf16x8 hv = *(const bf16x8*)(hp + l * 8);
    float v[8];
    float s1 = 0.f, s2 = 0.f;
#pragma unroll
    for (int e = 0; e < 8; ++e) { v[e] = (float)hv[e]; s1 += v[e]; s2 += v[e] * v[e]; }
#pragma unroll
    for (int m = 1; m < 32; m <<= 1) { s1 += __shfl_xor(s1, m, 64); s2 += __shfl_xor(s2, m, 64); }
    const float mu = s1 * (1.0f / 256.0f);
    const float rstd = rsqrtf(s2 * (1.0f / 256.0f) - mu * mu + 1e-5f);
    const float4 g0 = *(const float4*)(g + l * 8);
    const float4 g1 = *(const float4*)(g + l * 8 + 4);
    const float4 b0 = *(const float4*)(be + l * 8);
    const float4 b1 = *(const float4*)(be + l * 8 + 4);
    bf16x8 o;
    o[0] = (bf16)((v[0] - mu) * rstd * g0.x + b0.x);
    o[1] = (bf16)((v[1] - mu) * rstd * g0.y + b0.y);
    o[2] = (bf16)((v[2] - mu) * rstd * g0.z + b0.z);
    o[3] = (bf16)((v[3] - mu) * rstd * g0.w + b0.w);
    o[4] = (bf16)((v[4] - mu) * rstd * g1.x + b1.x);
    o[5] = (bf16)((v[5] - mu) * rstd * g1.y + b1.y);
    o[6] = (bf16)((v[6] - mu) * rstd * g1.z + b1.z);
    o[7] = (bf16)((v[7] - mu) * rstd * g1.w + b1.w);
    *(bf16x8*)(hp + l * 8) = o;
}

// ---------------- SE MLP (pool finish: sum 72 m-block partials per batch) ----------------
__global__ void se_kernel(const float* __restrict__ ppart,
                          const float* __restrict__ w1, const float* __restrict__ b1,
                          const float* __restrict__ w2, const float* __restrict__ b2,
                          float* __restrict__ sbuf)
{
    const int b = blockIdx.x, t = threadIdx.x;
    __shared__ float p[1152];
    __shared__ float t1[144];
    for (int c = t; c < 1152; c += 256) {
        float s = 0.f;
#pragma unroll 8
        for (int j = 0; j < 72; ++j) s += ppart[(size_t)(b * 72 + j) * 1152 + c];
        p[c] = s * (1.0f / 9216.0f);
    }
    __syncthreads();
    if (t < 144) {
        float a = b1[t];
        for (int k = 0; k < 1152; ++k) a += p[k] * w1[k * 144 + t];
        t1[t] = a > 0.f ? a : 0.f;
    }
    __syncthreads();
    for (int c = t; c < 1152; c += 256) {
        float a = b2[c];
#pragma unroll 8
        for (int k = 0; k < 144; ++k) a += t1[k] * w2[k * 1152 + c];
        sbuf[b * 1152 + c] = 1.0f / (1.0f + expf(-a));
    }
}

// ---------------- windowed self-attention ----------------
__device__ __forceinline__ int fswz(int r) { return (r & 7) ^ ((r >> 3) & 3); }

#define OSTG_STRIDE 388

__global__ void attn_kernel(const bf16* __restrict__ Y, const float* __restrict__ sbuf,
                            float* __restrict__ out)
{
    __shared__ __align__(16) char smem[24576 + 24832 + 2048];
    bf16*  yw   = (bf16*)smem;
    float* SpF  = (float*)(smem + 24576);
    float* ostg = (float*)(smem + 24576);
    bf16*  P    = (bf16*)(smem + 24576 + 24832);

    const int t = threadIdx.x;
    const int w = t >> 6, l = t & 63;
    const int l15 = l & 15, l4 = l >> 4;
    const int wdx = blockIdx.x, b = blockIdx.y;

    const bf16* Yp = Y + ((size_t)b * 9216 + (size_t)wdx * 32) * 1152;
    const float* sv = sbuf + b * 1152;
    float* op = out + ((size_t)b * 9216 + (size_t)wdx * 32) * 1152;

    auto stage_chunk = [&](int cc) {
#pragma unroll
        for (int i = 0; i < 6; ++i) {
            const int flat = i * 256 + t;
            const int r = flat / 48;
            const int gg = flat - r * 48;
            const int c0 = cc * 384 + gg * 8;
            const bf16x8 yv = *(const bf16x8*)(Yp + (size_t)r * 1152 + c0);
            const float4 sa = *(const float4*)(sv + c0);
            const float4 sb = *(const float4*)(sv + c0 + 4);
            bf16x8 ov;
            ov[0] = (bf16)((float)yv[0] * sa.x);
            ov[1] = (bf16)((float)yv[1] * sa.y);
            ov[2] = (bf16)((float)yv[2] * sa.z);
            ov[3] = (bf16)((float)yv[3] * sa.w);
            ov[4] = (bf16)((float)yv[4] * sb.x);
            ov[5] = (bf16)((float)yv[5] * sb.y);
            ov[6] = (bf16)((float)yv[6] * sb.z);
            ov[7] = (bf16)((float)yv[7] * sb.w);
            *(bf16x8*)&yw[((r * 48) + (gg ^ fswz(r))) << 3] = ov;
        }
    };

    f32x4 acc[2][2] = {};
    for (int cc = 0; cc < 3; ++cc) {
        if (cc) __syncthreads();
        stage_chunk(cc);
        __syncthreads();
#pragma unroll
        for (int kkl = 0; kkl < 3; ++kkl) {
            const int g = ((w * 3 + kkl) << 2) + l4;
            bf16x8 af[2];
#pragma unroll
            for (int i = 0; i < 2; ++i) {
                const int r = (i << 4) + l15;
                af[i] = *(const bf16x8*)&yw[((r * 48) + (g ^ fswz(r))) << 3];
            }
#pragma unroll
            for (int i = 0; i < 2; ++i)
#pragma unroll
                for (int j = 0; j < 2; ++j)
                    acc[i][j] = __builtin_amdgcn_mfma_f32_16x16x32_bf16(af[i], af[j], acc[i][j], 0, 0, 0);
        }
    }
#pragma unroll
    for (int i = 0; i < 2; ++i)
#pragma unroll
        for (int j = 0; j < 2; ++j)
#pragma unroll
            for (int r = 0; r < 4; ++r)
                SpF[w * 1056 + ((i << 4) + (l4 << 2) + r) * 33 + (j << 4) + l15] = acc[i][j][r];
    __syncthreads();

    {
        const int q = t >> 3, u = t & 7;
        float v[4];
#pragma unroll
        for (int e = 0; e < 4; ++e) {
            const int k2 = (u << 2) + e;
            v[e] = (SpF[q * 33 + k2] + SpF[1056 + q * 33 + k2] +
                    SpF[2112 + q * 33 + k2] + SpF[3168 + q * 33 + k2]) * 0.029462782549439483f;
        }
        float mx = fmaxf(fmaxf(v[0], v[1]), fmaxf(v[2], v[3]));
#pragma unroll
        for (int m = 1; m < 8; m <<= 1) mx = fmaxf(mx, __shfl_xor(mx, m, 64));
        float sm = 0.f;
#pragma unroll
        for (int e = 0; e < 4; ++e) { v[e] = expf(v[e] - mx); sm += v[e]; }
#pragma unroll
        for (int m = 1; m < 8; m <<= 1) sm += __shfl_xor(sm, m, 64);
        const float inv = 1.0f / sm;
#pragma unroll
        for (int e = 0; e < 4; ++e) P[(q << 5) + (u << 2) + e] = (bf16)(v[e] * inv);
    }
    __syncthreads();

    bf16x8 pa[2];
#pragma unroll
    for (int i = 0; i < 2; ++i)
        pa[i] = *(const bf16x8*)&P[(((i << 4) + l15) << 5) + (l4 << 3)];

    for (int ci = 0; ci < 3; ++ci) {
        const int cc = (ci == 0) ? 2 : (ci - 1);
        if (ci) {
            __syncthreads();
            stage_chunk(cc);
            __syncthreads();
        }
        f32x4 pacc[2][6] = {};
#pragma unroll
        for (int jn = 0; jn < 6; ++jn) {
            const int nl = w * 96 + (jn << 4) + l15;
            const int gg = nl >> 3, e = nl & 7;
            bf16x8 bv;
#pragma unroll
            for (int j = 0; j < 8; ++j) {
                const int kr = (l4 << 3) + j;
                bv[j] = yw[(((kr * 48) + (gg ^ fswz(kr))) << 3) + e];
            }
#pragma unroll
            for (int i = 0; i < 2; ++i)
                pacc[i][jn] = __builtin_amdgcn_mfma_f32_16x16x32_bf16(pa[i], bv, pacc[i][jn], 0, 0, 0);
        }
#pragma unroll
        for (int half = 0; half < 2; ++half) {
            if (half) __syncthreads();
#pragma unroll
            for (int jn = 0; jn < 6; ++jn)
#pragma unroll
                for (int r = 0; r < 4; ++r)
                    ostg[((l4 << 2) + r) * OSTG_STRIDE + w * 96 + (jn << 4) + l15] =
                        pacc[half][jn][r];
            __syncthreads();
            {
                const int row = t >> 4;
                const int cb = (t & 15) << 2;
                float* orow = op + (size_t)(row + (half << 4)) * 1152 + cc * 384;
                const float* srow = &ostg[row * OSTG_STRIDE];
#pragma unroll
                for (int k2 = 0; k2 < 6; ++k2) {
                    const int c = cb + (k2 << 6);
                    *(float4*)(orow + c) = *(const float4*)(srow + c);
                }
            }
        }
        if (ci < 2) __syncthreads();
    }
}

// ---------------- launcher ----------------
extern "C" void kernel_launch(void* const* d_in, const int* in_sizes, int n_in,
                              void* d_out, int out_size, void* d_ws, size_t ws_size,
                              hipStream_t stream)
{
    const float* x   = (const float*)d_in[0];
    const float* W1  = (const float*)d_in[1];
    const float* b1  = (const float*)d_in[2];
    const float* g1  = (const float*)d_in[3];
    const float* be1 = (const float*)d_in[4];
    const float* W2  = (const float*)d_in[5];
    const float* b2  = (const float*)d_in[6];
    const float* g2  = (const float*)d_in[7];
    const float* be2 = (const float*)d_in[8];
    const float* W3  = (const float*)d_in[9];
    const float* b3  = (const float*)d_in[10];
    const float* g3  = (const float*)d_in[11];
    const float* be3 = (const float*)d_in[12];
    const float* Wo  = (const float*)d_in[13];
    const float* bo  = (const float*)d_in[14];
    const float* cw1 = (const float*)d_in[15];
    const float* cb1 = (const float*)d_in[16];
    const float* cw2 = (const float*)d_in[17];
    const float* cb2 = (const float*)d_in[18];
    float* out = (float*)d_out;

    const int M = 8 * 9216;  // 73728 rows
    size_t off = 0;
    auto alloc = [&](size_t nbytes) {
        void* p = (char*)d_ws + off;
        off += (nbytes + 255) & ~(size_t)255;
        return p;
    };
    bf16* Yb  = (bf16*)alloc((size_t)M * 1152 * 2);
    bf16* Hb  = (bf16*)alloc((size_t)M * 768 * 2);   // H1; later reused as H3
    bf16* H2  = (bf16*)alloc((size_t)M * 512 * 2);
    bf16* Wt1 = (bf16*)alloc(768ull * 1152 * 2);
    bf16* Wt2 = (bf16*)alloc(512ull * 768 * 2);
    bf16* Wt3 = (bf16*)alloc(256ull * 512 * 2);
    bf16* Wto = (bf16*)alloc(1152ull * 256 * 2);
    float* ppart = (float*)alloc(576ull * 1152 * 4);
    float* sbuf  = (float*)alloc(8ull * 1152 * 4);
    bf16* H1 = Hb;
    bf16* H3 = Hb;

    wtrans_all_kernel<<<416, 256, 0, stream>>>(W1, Wt1, W2, Wt2, W3, Wt3, Wo, Wto);

    gemm_f32a_kernel<<<6 * 576, 256, 0, stream>>>(x, Wt1, b1, H1, 1152, 768, 6);
    ln768_kernel<<<M / 2, 256, 0, stream>>>(H1, g1, be1);
    gemm_bf16_kernel<<<4 * 576, 256, 0, stream>>>(H1, Wt2, b2, H2, 768, 512, 4, 1);
    ln512_kernel<<<M / 4, 256, 0, stream>>>(H2, g2, be2);
    gemm_bf16_kernel<<<2 * 576, 256, 0, stream>>>(H2, Wt3, b3, H3, 512, 256, 2, 1);
    ln256_kernel<<<M / 8, 256, 0, stream>>>(H3, g3, be3);
    gemm_pool_kernel<<<9 * 576, 256, 0, stream>>>(H3, Wto, bo, Yb, 256, 1152, 9, ppart);

    se_kernel<<<8, 256, 0, stream>>>(ppart, cw1, cb1, cw2, cb2, sbuf);
    attn_kernel<<<dim3(288, 8), 256, 0, stream>>>(Yb, sbuf, out);
}